// Round 2
// baseline (241.612 us; speedup 1.0000x reference)
//
#include <hip/hip_runtime.h>

typedef short bf16x8 __attribute__((ext_vector_type(8)));
typedef float f32x4 __attribute__((ext_vector_type(4)));
typedef unsigned short u16;
typedef unsigned int u32;

constexpr int B = 4, C = 512, T = 2048, H = 8, G = 32;
constexpr int CH = C / H;   // 64
constexpr int CPG = C / G;  // 16
constexpr float EPS = 1e-5f;

__device__ __forceinline__ u16 f2bf(float f) {
  union { float f; u32 u; } v; v.f = f;
  return (u16)((v.u + 0x7FFFu + ((v.u >> 16) & 1u)) >> 16);
}

__device__ __forceinline__ void gload16(const void* g, void* lds) {
  __builtin_amdgcn_global_load_lds(
      (const __attribute__((address_space(1))) void*)g,
      (__attribute__((address_space(3))) void*)lds, 16, 0, 0);
}

// Stage ROWS x 64 bf16 tile (row-major, row stride ldk elems) into linear LDS [ROWS][64].
// LDS dest is wave-uniform base + lane*16 (HW semantics of global_load_lds).
template <int ROWS>
__device__ __forceinline__ void stage_tile(u16* lds, const u16* gsrc, int ldk) {
  const int tid = threadIdx.x;
  const int w = tid >> 6, lane = tid & 63;
#pragma unroll
  for (int i = 0; i < ROWS / 32; ++i) {
    const int chunk = i * 4 + w;                 // 1KB chunk = 8 rows of 128B
    const int row = chunk * 8 + (lane >> 3);
    const u16* g = gsrc + (size_t)row * ldk + (lane & 7) * 8;
    gload16(g, (char*)lds + chunk * 1024);
  }
}

// ---------------- GroupNorm ----------------
__global__ __launch_bounds__(256) void gn_stats_k(const float* __restrict__ x,
                                                  float* __restrict__ stats) {
  const int bg = blockIdx.x;  // b*G + g ; group = 16 contiguous channels
  const float4* xp = (const float4*)(x + (size_t)bg * CPG * T);
  float s = 0.f, ss = 0.f;
  for (int i = threadIdx.x; i < CPG * T / 4; i += 256) {
    float4 v = xp[i];
    s += v.x + v.y + v.z + v.w;
    ss += v.x * v.x + v.y * v.y + v.z * v.z + v.w * v.w;
  }
  for (int off = 32; off; off >>= 1) {
    s += __shfl_down(s, off);
    ss += __shfl_down(ss, off);
  }
  __shared__ float red[8];
  const int w = threadIdx.x >> 6;
  if ((threadIdx.x & 63) == 0) { red[w] = s; red[4 + w] = ss; }
  __syncthreads();
  if (threadIdx.x == 0) {
    float S = red[0] + red[1] + red[2] + red[3];
    float SS = red[4] + red[5] + red[6] + red[7];
    const float inv = 1.f / (float)(CPG * T);
    float mean = S * inv;
    float var = SS * inv - mean * mean;
    stats[bg * 2] = mean;
    stats[bg * 2 + 1] = rsqrtf(var + EPS);
  }
}

// normalize + write transposed h_t[b][t][c] (bf16)
__global__ __launch_bounds__(256) void gn_apply_k(const float* __restrict__ x,
                                                  const float* __restrict__ stats,
                                                  const float* __restrict__ gsc,
                                                  const float* __restrict__ gbi,
                                                  u16* __restrict__ ht) {
  const int b = blockIdx.y;
  const int t0 = blockIdx.x * 32;
#pragma unroll
  for (int p = 0; p < 2; ++p) {
    const int c = p * 256 + threadIdx.x;
    const int bg = b * G + (c >> 4);
    const float mean = stats[bg * 2], rstd = stats[bg * 2 + 1];
    const float sc = gsc[c] * rstd;
    const float bi = gbi[c] - mean * sc;
    const float4* xp = (const float4*)(x + ((size_t)b * C + c) * T + t0);
#pragma unroll
    for (int j = 0; j < 8; ++j) {
      float4 v = xp[j];
      const int t = t0 + j * 4;
      u16* hp = ht + ((size_t)b * T + t) * C + c;
      hp[0]     = f2bf(v.x * sc + bi);
      hp[C]     = f2bf(v.y * sc + bi);
      hp[2 * C] = f2bf(v.z * sc + bi);
      hp[3 * C] = f2bf(v.w * sc + bi);
    }
  }
}

// ---------------- fp32 -> bf16 weight cast ----------------
__global__ __launch_bounds__(256) void cast_bf_k(const float* __restrict__ src,
                                                 u16* __restrict__ dst, int n4) {
  int i = blockIdx.x * 256 + threadIdx.x;
  if (i < n4) {
    float4 v = ((const float4*)src)[i];
    uint2 pk;
    pk.x = (u32)f2bf(v.x) | ((u32)f2bf(v.y) << 16);
    pk.y = (u32)f2bf(v.z) | ((u32)f2bf(v.w) << 16);
    ((uint2*)dst)[i] = pk;
  }
}

// ---------------- QKV bt-GEMM: C'[t][o] = sum_c h_t[t][c] * W[o][c] ----------------
__global__ __launch_bounds__(256) void qkv_gemm_k(const u16* __restrict__ ht,
                                                  const u16* __restrict__ wq,
                                                  const float* __restrict__ qkvb,
                                                  u16* __restrict__ qo,
                                                  u16* __restrict__ kvo_k,
                                                  u16* __restrict__ kvo_v) {
  __shared__ u16 As[128 * 64];
  __shared__ u16 Bs[128 * 64];
  const int mt = blockIdx.x, nt = blockIdx.y, b = blockIdx.z;
  const u16* Ab = ht + ((size_t)b * T + mt * 128) * C;
  const u16* Bb = wq + (size_t)nt * 128 * C;
  const int tid = threadIdx.x, lane = tid & 63, w = tid >> 6;
  const int wr = w >> 1, wc = w & 1, l15 = lane & 15, lhi = lane >> 4;

  const f32x4 vzero = {0.f, 0.f, 0.f, 0.f};
  f32x4 acc[4][4];
#pragma unroll
  for (int m = 0; m < 4; ++m)
#pragma unroll
    for (int n = 0; n < 4; ++n) acc[m][n] = vzero;

  for (int kt = 0; kt < C / 64; ++kt) {
    stage_tile<128>(As, Ab + kt * 64, C);
    stage_tile<128>(Bs, Bb + kt * 64, C);
    __syncthreads();
#pragma unroll
    for (int kk = 0; kk < 2; ++kk) {
      const int koff = kk * 32 + lhi * 8;
      bf16x8 af[4], bfv[4];
#pragma unroll
      for (int m = 0; m < 4; ++m)
        af[m] = *(const bf16x8*)&As[(wr * 64 + m * 16 + l15) * 64 + koff];
#pragma unroll
      for (int n = 0; n < 4; ++n)
        bfv[n] = *(const bf16x8*)&Bs[(wc * 64 + n * 16 + l15) * 64 + koff];
#pragma unroll
      for (int m = 0; m < 4; ++m)
#pragma unroll
        for (int n = 0; n < 4; ++n)
          acc[m][n] = __builtin_amdgcn_mfma_f32_16x16x32_bf16(af[m], bfv[n], acc[m][n], 0, 0, 0);
    }
    __syncthreads();
  }
  // epilogue: scatter to q[bh][t][64], k[bh][t][64], v[bh][64][t]
#pragma unroll
  for (int n = 0; n < 4; ++n) {
    const int o = nt * 128 + wc * 64 + n * 16 + l15;
    const float bias = qkvb[o];
    const int which = o >> 9, rem = o & 511, hh = rem >> 6, d = rem & 63;
    const size_t bh = (size_t)b * H + hh;
#pragma unroll
    for (int m = 0; m < 4; ++m) {
      const int tbase = mt * 128 + wr * 64 + m * 16 + lhi * 4;
#pragma unroll
      for (int r = 0; r < 4; ++r) {
        const u16 bv = f2bf(acc[m][n][r] + bias);
        const int t = tbase + r;
        if (which == 0)      qo[(bh * T + t) * CH + d] = bv;
        else if (which == 1) kvo_k[(bh * T + t) * CH + d] = bv;
        else                 kvo_v[(bh * CH + d) * T + t] = bv;
      }
    }
  }
}

// ---------------- flash attention: 32 bh x 32 q-tiles of 64 ----------------
__global__ __launch_bounds__(256) void attn_k(const u16* __restrict__ q,
                                              const u16* __restrict__ k,
                                              const u16* __restrict__ v,
                                              u16* __restrict__ at) {
  __shared__ u16 Qs[64 * 64], Ks[64 * 64], Vs[64 * 64], Ps[64 * 64];
  const int qt = blockIdx.x, bh = blockIdx.y;
  const int tid = threadIdx.x, lane = tid & 63, w = tid >> 6;
  const int l15 = lane & 15, lhi = lane >> 4;
  const u16* qb = q + (size_t)bh * T * CH;
  const u16* kb = k + (size_t)bh * T * CH;
  const u16* vb = v + (size_t)bh * CH * T;

  stage_tile<64>(Qs, qb + qt * 64 * CH, CH);
  stage_tile<64>(Ks, kb, CH);
  stage_tile<64>(Vs, vb, T);  // V is [d][t]; tile = rows d, cols s
  __syncthreads();

  bf16x8 aq[2];
  aq[0] = *(const bf16x8*)&Qs[(w * 16 + l15) * 64 + lhi * 8];
  aq[1] = *(const bf16x8*)&Qs[(w * 16 + l15) * 64 + 32 + lhi * 8];

  const f32x4 vzero = {0.f, 0.f, 0.f, 0.f};
  f32x4 accO[4];
#pragma unroll
  for (int n = 0; n < 4; ++n) accO[n] = vzero;
  float mprev[4] = {-1e30f, -1e30f, -1e30f, -1e30f};
  float lsum[4] = {0.f, 0.f, 0.f, 0.f};

  for (int it = 0; it < T / 64; ++it) {
    f32x4 accS[4];
#pragma unroll
    for (int n = 0; n < 4; ++n) accS[n] = vzero;
#pragma unroll
    for (int kk = 0; kk < 2; ++kk) {
      const int koff = kk * 32 + lhi * 8;
#pragma unroll
      for (int n = 0; n < 4; ++n) {
        bf16x8 bk = *(const bf16x8*)&Ks[(n * 16 + l15) * 64 + koff];
        accS[n] = __builtin_amdgcn_mfma_f32_16x16x32_bf16(aq[kk], bk, accS[n], 0, 0, 0);
      }
    }
    // online softmax over rows (lhi*4 + r); 16-lane group shfl reductions
#pragma unroll
    for (int r = 0; r < 4; ++r) {
      float sv0 = accS[0][r] * 0.125f, sv1 = accS[1][r] * 0.125f;
      float sv2 = accS[2][r] * 0.125f, sv3 = accS[3][r] * 0.125f;
      float mx = fmaxf(fmaxf(sv0, sv1), fmaxf(sv2, sv3));
      mx = fmaxf(mx, __shfl_xor(mx, 1));
      mx = fmaxf(mx, __shfl_xor(mx, 2));
      mx = fmaxf(mx, __shfl_xor(mx, 4));
      mx = fmaxf(mx, __shfl_xor(mx, 8));
      const float mnew = fmaxf(mprev[r], mx);
      const float al = __expf(mprev[r] - mnew);
      float p0 = __expf(sv0 - mnew), p1 = __expf(sv1 - mnew);
      float p2 = __expf(sv2 - mnew), p3 = __expf(sv3 - mnew);
      float ps = p0 + p1 + p2 + p3;
      ps += __shfl_xor(ps, 1);
      ps += __shfl_xor(ps, 2);
      ps += __shfl_xor(ps, 4);
      ps += __shfl_xor(ps, 8);
      lsum[r] = lsum[r] * al + ps;
      mprev[r] = mnew;
      accO[0][r] *= al; accO[1][r] *= al; accO[2][r] *= al; accO[3][r] *= al;
      u16* pp = Ps + (w * 16 + lhi * 4 + r) * 64 + l15;
      pp[0] = f2bf(p0); pp[16] = f2bf(p1); pp[32] = f2bf(p2); pp[48] = f2bf(p3);
    }
    // PV: O[q][d] += P[q][s] * V[s][d], V from Vs[d][s] (bt-form)
#pragma unroll
    for (int kk = 0; kk < 2; ++kk) {
      const int koff = kk * 32 + lhi * 8;
      bf16x8 ap = *(const bf16x8*)&Ps[(w * 16 + l15) * 64 + koff];
#pragma unroll
      for (int n = 0; n < 4; ++n) {
        bf16x8 bv = *(const bf16x8*)&Vs[(n * 16 + l15) * 64 + koff];
        accO[n] = __builtin_amdgcn_mfma_f32_16x16x32_bf16(ap, bv, accO[n], 0, 0, 0);
      }
    }
    __syncthreads();
    if (it + 1 < T / 64) {
      stage_tile<64>(Ks, kb + (size_t)(it + 1) * 64 * CH, CH);
      stage_tile<64>(Vs, vb + (it + 1) * 64, T);
    }
    __syncthreads();
  }
  // write a_t[b][t][c] bf16
  const int bq = bh >> 3, hh = bh & 7;
#pragma unroll
  for (int n = 0; n < 4; ++n) {
#pragma unroll
    for (int r = 0; r < 4; ++r) {
      const int t = qt * 64 + w * 16 + lhi * 4 + r;
      const int c = hh * CH + n * 16 + l15;
      at[((size_t)bq * T + t) * C + c] = f2bf(accO[n][r] / lsum[r]);
    }
  }
}

// ---------------- proj bt-GEMM + bias + residual ----------------
__global__ __launch_bounds__(256) void proj_gemm_k(const u16* __restrict__ at,
                                                   const u16* __restrict__ wp,
                                                   const float* __restrict__ pb,
                                                   const float* __restrict__ x,
                                                   float* __restrict__ out) {
  __shared__ u16 As[128 * 64];
  __shared__ u16 Bs[128 * 64];
  const int mt = blockIdx.x, nt = blockIdx.y, b = blockIdx.z;
  const u16* Ab = at + ((size_t)b * T + mt * 128) * C;
  const u16* Bb = wp + (size_t)nt * 128 * C;
  const int tid = threadIdx.x, lane = tid & 63, w = tid >> 6;
  const int wr = w >> 1, wc = w & 1, l15 = lane & 15, lhi = lane >> 4;

  const f32x4 vzero = {0.f, 0.f, 0.f, 0.f};
  f32x4 acc[4][4];
#pragma unroll
  for (int m = 0; m < 4; ++m)
#pragma unroll
    for (int n = 0; n < 4; ++n) acc[m][n] = vzero;

  for (int kt = 0; kt < C / 64; ++kt) {
    stage_tile<128>(As, Ab + kt * 64, C);
    stage_tile<128>(Bs, Bb + kt * 64, C);
    __syncthreads();
#pragma unroll
    for (int kk = 0; kk < 2; ++kk) {
      const int koff = kk * 32 + lhi * 8;
      bf16x8 af[4], bfv[4];
#pragma unroll
      for (int m = 0; m < 4; ++m)
        af[m] = *(const bf16x8*)&As[(wr * 64 + m * 16 + l15) * 64 + koff];
#pragma unroll
      for (int n = 0; n < 4; ++n)
        bfv[n] = *(const bf16x8*)&Bs[(wc * 64 + n * 16 + l15) * 64 + koff];
#pragma unroll
      for (int m = 0; m < 4; ++m)
#pragma unroll
        for (int n = 0; n < 4; ++n)
          acc[m][n] = __builtin_amdgcn_mfma_f32_16x16x32_bf16(af[m], bfv[n], acc[m][n], 0, 0, 0);
    }
    __syncthreads();
  }
#pragma unroll
  for (int n = 0; n < 4; ++n) {
    const int o = nt * 128 + wc * 64 + n * 16 + l15;
    const float bias = pb[o];
#pragma unroll
    for (int m = 0; m < 4; ++m) {
      const int tbase = mt * 128 + wr * 64 + m * 16 + lhi * 4;
#pragma unroll
      for (int r = 0; r < 4; ++r) {
        const int t = tbase + r;
        const size_t idx = ((size_t)b * C + o) * T + t;
        out[idx] = x[idx] + acc[m][n][r] + bias;
      }
    }
  }
}

extern "C" void kernel_launch(void* const* d_in, const int* in_sizes, int n_in,
                              void* d_out, int out_size, void* d_ws, size_t ws_size,
                              hipStream_t stream) {
  const float* x     = (const float*)d_in[0];
  const float* gsc   = (const float*)d_in[1];
  const float* gbi   = (const float*)d_in[2];
  const float* qkvw  = (const float*)d_in[3];
  const float* qkvb  = (const float*)d_in[4];
  const float* projw = (const float*)d_in[5];
  const float* projb = (const float*)d_in[6];
  float* out = (float*)d_out;

  char* ws = (char*)d_ws;
  // layout (bytes): stats 1K | wq 1.5M | wp 0.5M | ht 8M | q 8M | k 8M | v 8M  (~35.7MB)
  float* stats = (float*)ws;
  u16* wq = (u16*)(ws + 1024);
  u16* wp = (u16*)(ws + 1024 + 1572864);
  u16* ht = (u16*)(ws + 2098176);
  u16* qo = (u16*)(ws + 10486784);
  u16* ko = (u16*)(ws + 18875392);
  u16* vo = (u16*)(ws + 27264000);
  u16* at = ht;  // reuse: ht dead after qkv_gemm

  cast_bf_k<<<768, 256, 0, stream>>>(qkvw, wq, 196608);
  cast_bf_k<<<256, 256, 0, stream>>>(projw, wp, 65536);
  gn_stats_k<<<B * G, 256, 0, stream>>>(x, stats);
  gn_apply_k<<<dim3(T / 32, B), 256, 0, stream>>>(x, stats, gsc, gbi, ht);
  qkv_gemm_k<<<dim3(T / 128, (3 * C) / 128, B), 256, 0, stream>>>(ht, wq, qkvb, qo, ko, vo);
  attn_k<<<dim3(T / 64, B * H), 256, 0, stream>>>(qo, ko, vo, at);
  proj_gemm_k<<<dim3(T / 128, C / 128, B), 256, 0, stream>>>(at, wp, projb, x, out);
}

// Round 3
// 193.305 us; speedup vs baseline: 1.2499x; 1.2499x over previous
//
#include <hip/hip_runtime.h>

typedef short bf16x8 __attribute__((ext_vector_type(8)));
typedef float f32x4 __attribute__((ext_vector_type(4)));
typedef unsigned short u16;
typedef unsigned int u32;

constexpr int B = 4, C = 512, T = 2048, H = 8, G = 32;
constexpr int CH = C / H;   // 64
constexpr int CPG = C / G;  // 16
constexpr float EPS = 1e-5f;
constexpr float LOG2E = 1.44269504088896340736f;

__device__ __forceinline__ u16 f2bf(float f) {
  union { float f; u32 u; } v; v.f = f;
  return (u16)((v.u + 0x7FFFu + ((v.u >> 16) & 1u)) >> 16);
}

__device__ __forceinline__ void gload16(const void* g, void* lds) {
  __builtin_amdgcn_global_load_lds(
      (const __attribute__((address_space(1))) void*)g,
      (__attribute__((address_space(3))) void*)lds, 16, 0, 0);
}

// ---- XOR-swizzled staging: tile ROWS x 64 bf16, LDS linear [ROWS][64].
// LDS dest = wave-uniform base + lane*16 (HW). We pre-swizzle the GLOBAL
// source column so that a swizzled read (col8 ^ (row&7)<<3) returns the
// correct data (rule #21: both-sides-or-neither).
template <int ROWS>  // 256-thread version (GEMMs)
__device__ __forceinline__ void stage_swz_4w(u16* lds, const u16* gsrc, int ldk) {
  const int tid = threadIdx.x;
  const int w = tid >> 6, lane = tid & 63;
#pragma unroll
  for (int i = 0; i < ROWS / 32; ++i) {
    const int chunk = i * 4 + w;                 // 1KB chunk = 8 rows of 128B
    const int row = chunk * 8 + (lane >> 3);
    const int col = ((lane & 7) * 8) ^ ((row & 7) << 3);
    gload16(gsrc + (size_t)row * ldk + col, (char*)lds + chunk * 1024);
  }
}

template <int ROWS>  // 512-thread version (attention)
__device__ __forceinline__ void stage_swz_8w(u16* lds, const u16* gsrc, int ldk) {
  const int tid = threadIdx.x;
  const int w = tid >> 6, lane = tid & 63;
#pragma unroll
  for (int i = 0; i < ROWS / 64; ++i) {
    const int chunk = i * 8 + w;
    const int row = chunk * 8 + (lane >> 3);
    const int col = ((lane & 7) * 8) ^ ((row & 7) << 3);
    gload16(gsrc + (size_t)row * ldk + col, (char*)lds + chunk * 1024);
  }
}

// ---------------- GroupNorm ----------------
__global__ __launch_bounds__(256) void gn_stats_k(const float* __restrict__ x,
                                                  float* __restrict__ stats) {
  const int bg = blockIdx.x;
  const float4* xp = (const float4*)(x + (size_t)bg * CPG * T);
  float s = 0.f, ss = 0.f;
  for (int i = threadIdx.x; i < CPG * T / 4; i += 256) {
    float4 v = xp[i];
    s += v.x + v.y + v.z + v.w;
    ss += v.x * v.x + v.y * v.y + v.z * v.z + v.w * v.w;
  }
  for (int off = 32; off; off >>= 1) {
    s += __shfl_down(s, off);
    ss += __shfl_down(ss, off);
  }
  __shared__ float red[8];
  const int w = threadIdx.x >> 6;
  if ((threadIdx.x & 63) == 0) { red[w] = s; red[4 + w] = ss; }
  __syncthreads();
  if (threadIdx.x == 0) {
    float S = red[0] + red[1] + red[2] + red[3];
    float SS = red[4] + red[5] + red[6] + red[7];
    const float inv = 1.f / (float)(CPG * T);
    float mean = S * inv;
    float var = SS * inv - mean * mean;
    stats[bg * 2] = mean;
    stats[bg * 2 + 1] = rsqrtf(var + EPS);
  }
}

__global__ __launch_bounds__(256) void gn_apply_k(const float* __restrict__ x,
                                                  const float* __restrict__ stats,
                                                  const float* __restrict__ gsc,
                                                  const float* __restrict__ gbi,
                                                  u16* __restrict__ ht) {
  const int b = blockIdx.y;
  const int t0 = blockIdx.x * 32;
#pragma unroll
  for (int p = 0; p < 2; ++p) {
    const int c = p * 256 + threadIdx.x;
    const int bg = b * G + (c >> 4);
    const float mean = stats[bg * 2], rstd = stats[bg * 2 + 1];
    const float sc = gsc[c] * rstd;
    const float bi = gbi[c] - mean * sc;
    const float4* xp = (const float4*)(x + ((size_t)b * C + c) * T + t0);
#pragma unroll
    for (int j = 0; j < 8; ++j) {
      float4 v = xp[j];
      const int t = t0 + j * 4;
      u16* hp = ht + ((size_t)b * T + t) * C + c;
      hp[0]     = f2bf(v.x * sc + bi);
      hp[C]     = f2bf(v.y * sc + bi);
      hp[2 * C] = f2bf(v.z * sc + bi);
      hp[3 * C] = f2bf(v.w * sc + bi);
    }
  }
}

// ---------------- fp32 -> bf16 weight cast ----------------
__global__ __launch_bounds__(256) void cast_bf_k(const float* __restrict__ src,
                                                 u16* __restrict__ dst, int n4) {
  int i = blockIdx.x * 256 + threadIdx.x;
  if (i < n4) {
    float4 v = ((const float4*)src)[i];
    uint2 pk;
    pk.x = (u32)f2bf(v.x) | ((u32)f2bf(v.y) << 16);
    pk.y = (u32)f2bf(v.z) | ((u32)f2bf(v.w) << 16);
    ((uint2*)dst)[i] = pk;
  }
}

// ---------------- QKV bt-GEMM: C'[t][o] = sum_c h_t[t][c] * W[o][c] ----------------
__global__ __launch_bounds__(256) void qkv_gemm_k(const u16* __restrict__ ht,
                                                  const u16* __restrict__ wq,
                                                  const float* __restrict__ qkvb,
                                                  u16* __restrict__ qo,
                                                  u16* __restrict__ kvo_k,
                                                  u16* __restrict__ kvo_v) {
  __shared__ u16 As[128 * 64];
  __shared__ u16 Bs[128 * 64];
  const int mt = blockIdx.x, nt = blockIdx.y, b = blockIdx.z;
  const u16* Ab = ht + ((size_t)b * T + mt * 128) * C;
  const u16* Bb = wq + (size_t)nt * 128 * C;
  const int tid = threadIdx.x, lane = tid & 63, w = tid >> 6;
  const int wr = w >> 1, wc = w & 1, l15 = lane & 15, lhi = lane >> 4;
  const int swz = (l15 & 7) << 3;

  const f32x4 vzero = {0.f, 0.f, 0.f, 0.f};
  f32x4 acc[4][4];
#pragma unroll
  for (int m = 0; m < 4; ++m)
#pragma unroll
    for (int n = 0; n < 4; ++n) acc[m][n] = vzero;

  for (int kt = 0; kt < C / 64; ++kt) {
    stage_swz_4w<128>(As, Ab + kt * 64, C);
    stage_swz_4w<128>(Bs, Bb + kt * 64, C);
    __syncthreads();
#pragma unroll
    for (int kk = 0; kk < 2; ++kk) {
      const int koff = (kk * 32 + lhi * 8) ^ swz;
      bf16x8 af[4], bfv[4];
#pragma unroll
      for (int m = 0; m < 4; ++m)
        af[m] = *(const bf16x8*)&As[(wr * 64 + m * 16 + l15) * 64 + koff];
#pragma unroll
      for (int n = 0; n < 4; ++n)
        bfv[n] = *(const bf16x8*)&Bs[(wc * 64 + n * 16 + l15) * 64 + koff];
#pragma unroll
      for (int m = 0; m < 4; ++m)
#pragma unroll
        for (int n = 0; n < 4; ++n)
          acc[m][n] = __builtin_amdgcn_mfma_f32_16x16x32_bf16(af[m], bfv[n], acc[m][n], 0, 0, 0);
    }
    __syncthreads();
  }
#pragma unroll
  for (int n = 0; n < 4; ++n) {
    const int o = nt * 128 + wc * 64 + n * 16 + l15;
    const float bias = qkvb[o];
    const int which = o >> 9, rem = o & 511, hh = rem >> 6, d = rem & 63;
    const size_t bh = (size_t)b * H + hh;
#pragma unroll
    for (int m = 0; m < 4; ++m) {
      const int tbase = mt * 128 + wr * 64 + m * 16 + lhi * 4;
#pragma unroll
      for (int r = 0; r < 4; ++r) {
        const u16 bv = f2bf(acc[m][n][r] + bias);
        const int t = tbase + r;
        if (which == 0)      qo[(bh * T + t) * CH + d] = bv;
        else if (which == 1) kvo_k[(bh * T + t) * CH + d] = bv;
        else                 kvo_v[(bh * CH + d) * T + t] = bv;
      }
    }
  }
}

// ---------------- flash attention: QBLK=128 (8 waves), KVBLK=64, dbuf K/V ----------------
__global__ __launch_bounds__(512) void attn_k(const u16* __restrict__ q,
                                              const u16* __restrict__ k,
                                              const u16* __restrict__ v,
                                              u16* __restrict__ at) {
  __shared__ u16 Qs[128 * 64];
  __shared__ u16 Ks[2][64 * 64];
  __shared__ u16 Vs[2][64 * 64];
  __shared__ u16 Ps[128 * 64];
  const int qt = blockIdx.x, bh = blockIdx.y;
  const int tid = threadIdx.x, lane = tid & 63, w = tid >> 6;
  const int l15 = lane & 15, lhi = lane >> 4;
  const int swz = (l15 & 7) << 3;
  const u16* qb = q + (size_t)bh * T * CH;
  const u16* kb = k + (size_t)bh * T * CH;
  const u16* vb = v + (size_t)bh * CH * T;

  stage_swz_8w<128>(Qs, qb + qt * 128 * CH, CH);
  stage_swz_8w<64>(Ks[0], kb, CH);
  stage_swz_8w<64>(Vs[0], vb, T);  // V is [d][t]; tile rows=d, cols=s
  __syncthreads();

  // wave w owns q-rows [w*16, w*16+16)
  bf16x8 aq[2];
  aq[0] = *(const bf16x8*)&Qs[(w * 16 + l15) * 64 + ((lhi * 8) ^ swz)];
  aq[1] = *(const bf16x8*)&Qs[(w * 16 + l15) * 64 + ((32 + lhi * 8) ^ swz)];

  const f32x4 vzero = {0.f, 0.f, 0.f, 0.f};
  f32x4 accO[4];
#pragma unroll
  for (int n = 0; n < 4; ++n) accO[n] = vzero;
  float mprev[4] = {-1e30f, -1e30f, -1e30f, -1e30f};
  float lsum[4] = {0.f, 0.f, 0.f, 0.f};
  constexpr float SCL = 0.125f * LOG2E;  // fold 1/sqrt(sqrt(64)))^2 and log2e; exp2-softmax == exp-softmax

  int cur = 0;
  for (int it = 0; it < T / 64; ++it) {
    // issue next K/V tile loads FIRST -> HBM latency hides under compute (T3 2-phase)
    if (it + 1 < T / 64) {
      stage_swz_8w<64>(Ks[cur ^ 1], kb + (size_t)(it + 1) * 64 * CH, CH);
      stage_swz_8w<64>(Vs[cur ^ 1], vb + (it + 1) * 64, T);
    }
    const u16* Kc = Ks[cur];
    const u16* Vc = Vs[cur];

    f32x4 accS[4];
#pragma unroll
    for (int n = 0; n < 4; ++n) accS[n] = vzero;
#pragma unroll
    for (int kk = 0; kk < 2; ++kk) {
      const int koff = (kk * 32 + lhi * 8) ^ swz;
#pragma unroll
      for (int n = 0; n < 4; ++n) {
        bf16x8 bk = *(const bf16x8*)&Kc[(n * 16 + l15) * 64 + koff];
        accS[n] = __builtin_amdgcn_mfma_f32_16x16x32_bf16(aq[kk], bk, accS[n], 0, 0, 0);
      }
    }
    // online softmax (base-2); rows lhi*4+r within wave block, 16-lane group reduce
#pragma unroll
    for (int r = 0; r < 4; ++r) {
      float sv0 = accS[0][r] * SCL, sv1 = accS[1][r] * SCL;
      float sv2 = accS[2][r] * SCL, sv3 = accS[3][r] * SCL;
      float mx = fmaxf(fmaxf(sv0, sv1), fmaxf(sv2, sv3));
      mx = fmaxf(mx, __shfl_xor(mx, 1));
      mx = fmaxf(mx, __shfl_xor(mx, 2));
      mx = fmaxf(mx, __shfl_xor(mx, 4));
      mx = fmaxf(mx, __shfl_xor(mx, 8));
      const float mnew = fmaxf(mprev[r], mx);
      const float al = exp2f(mprev[r] - mnew);
      float p0 = exp2f(sv0 - mnew), p1 = exp2f(sv1 - mnew);
      float p2 = exp2f(sv2 - mnew), p3 = exp2f(sv3 - mnew);
      float ps = p0 + p1 + p2 + p3;
      ps += __shfl_xor(ps, 1);
      ps += __shfl_xor(ps, 2);
      ps += __shfl_xor(ps, 4);
      ps += __shfl_xor(ps, 8);
      lsum[r] = lsum[r] * al + ps;
      mprev[r] = mnew;
      accO[0][r] *= al; accO[1][r] *= al; accO[2][r] *= al; accO[3][r] *= al;
      const int prow = w * 16 + lhi * 4 + r;
      u16* pp = Ps + prow * 64;
      const int pswz = (prow & 7) << 3;
      pp[l15 ^ pswz]        = f2bf(p0);
      pp[(l15 + 16) ^ pswz] = f2bf(p1);
      pp[(l15 + 32) ^ pswz] = f2bf(p2);
      pp[(l15 + 48) ^ pswz] = f2bf(p3);
    }
    // PV: O[q][d] += P[q][s] * V[s][d] (V staged bt-form [d][s])
#pragma unroll
    for (int kk = 0; kk < 2; ++kk) {
      const int koff = (kk * 32 + lhi * 8) ^ swz;
      bf16x8 ap = *(const bf16x8*)&Ps[(w * 16 + l15) * 64 + koff];
#pragma unroll
      for (int n = 0; n < 4; ++n) {
        bf16x8 bv = *(const bf16x8*)&Vc[(n * 16 + l15) * 64 + koff];
        accO[n] = __builtin_amdgcn_mfma_f32_16x16x32_bf16(ap, bv, accO[n], 0, 0, 0);
      }
    }
    __syncthreads();  // drains vmcnt: next tile staged; all waves done with cur bufs
    cur ^= 1;
  }
  // write a_t[b][t][c] bf16
  const int bq = bh >> 3, hh = bh & 7;
#pragma unroll
  for (int n = 0; n < 4; ++n) {
#pragma unroll
    for (int r = 0; r < 4; ++r) {
      const int t = qt * 128 + w * 16 + lhi * 4 + r;
      const int c = hh * CH + n * 16 + l15;
      at[((size_t)bq * T + t) * C + c] = f2bf(accO[n][r] / lsum[r]);
    }
  }
}

// ---------------- proj bt-GEMM + bias + residual ----------------
__global__ __launch_bounds__(256) void proj_gemm_k(const u16* __restrict__ at,
                                                   const u16* __restrict__ wp,
                                                   const float* __restrict__ pb,
                                                   const float* __restrict__ x,
                                                   float* __restrict__ out) {
  __shared__ u16 As[128 * 64];
  __shared__ u16 Bs[128 * 64];
  const int mt = blockIdx.x, nt = blockIdx.y, b = blockIdx.z;
  const u16* Ab = at + ((size_t)b * T + mt * 128) * C;
  const u16* Bb = wp + (size_t)nt * 128 * C;
  const int tid = threadIdx.x, lane = tid & 63, w = tid >> 6;
  const int wr = w >> 1, wc = w & 1, l15 = lane & 15, lhi = lane >> 4;
  const int swz = (l15 & 7) << 3;

  const f32x4 vzero = {0.f, 0.f, 0.f, 0.f};
  f32x4 acc[4][4];
#pragma unroll
  for (int m = 0; m < 4; ++m)
#pragma unroll
    for (int n = 0; n < 4; ++n) acc[m][n] = vzero;

  for (int kt = 0; kt < C / 64; ++kt) {
    stage_swz_4w<128>(As, Ab + kt * 64, C);
    stage_swz_4w<128>(Bs, Bb + kt * 64, C);
    __syncthreads();
#pragma unroll
    for (int kk = 0; kk < 2; ++kk) {
      const int koff = (kk * 32 + lhi * 8) ^ swz;
      bf16x8 af[4], bfv[4];
#pragma unroll
      for (int m = 0; m < 4; ++m)
        af[m] = *(const bf16x8*)&As[(wr * 64 + m * 16 + l15) * 64 + koff];
#pragma unroll
      for (int n = 0; n < 4; ++n)
        bfv[n] = *(const bf16x8*)&Bs[(wc * 64 + n * 16 + l15) * 64 + koff];
#pragma unroll
      for (int m = 0; m < 4; ++m)
#pragma unroll
        for (int n = 0; n < 4; ++n)
          acc[m][n] = __builtin_amdgcn_mfma_f32_16x16x32_bf16(af[m], bfv[n], acc[m][n], 0, 0, 0);
    }
    __syncthreads();
  }
#pragma unroll
  for (int n = 0; n < 4; ++n) {
    const int o = nt * 128 + wc * 64 + n * 16 + l15;
    const float bias = pb[o];
#pragma unroll
    for (int m = 0; m < 4; ++m) {
      const int tbase = mt * 128 + wr * 64 + m * 16 + lhi * 4;
#pragma unroll
      for (int r = 0; r < 4; ++r) {
        const int t = tbase + r;
        const size_t idx = ((size_t)b * C + o) * T + t;
        out[idx] = x[idx] + acc[m][n][r] + bias;
      }
    }
  }
}

extern "C" void kernel_launch(void* const* d_in, const int* in_sizes, int n_in,
                              void* d_out, int out_size, void* d_ws, size_t ws_size,
                              hipStream_t stream) {
  const float* x     = (const float*)d_in[0];
  const float* gsc   = (const float*)d_in[1];
  const float* gbi   = (const float*)d_in[2];
  const float* qkvw  = (const float*)d_in[3];
  const float* qkvb  = (const float*)d_in[4];
  const float* projw = (const float*)d_in[5];
  const float* projb = (const float*)d_in[6];
  float* out = (float*)d_out;

  char* ws = (char*)d_ws;
  float* stats = (float*)ws;
  u16* wq = (u16*)(ws + 1024);
  u16* wp = (u16*)(ws + 1024 + 1572864);
  u16* ht = (u16*)(ws + 2098176);
  u16* qo = (u16*)(ws + 10486784);
  u16* ko = (u16*)(ws + 18875392);
  u16* vo = (u16*)(ws + 27264000);
  u16* at = ht;  // reuse: ht dead after qkv_gemm

  cast_bf_k<<<768, 256, 0, stream>>>(qkvw, wq, 196608);
  cast_bf_k<<<256, 256, 0, stream>>>(projw, wp, 65536);
  gn_stats_k<<<B * G, 256, 0, stream>>>(x, stats);
  gn_apply_k<<<dim3(T / 32, B), 256, 0, stream>>>(x, stats, gsc, gbi, ht);
  qkv_gemm_k<<<dim3(T / 128, (3 * C) / 128, B), 256, 0, stream>>>(ht, wq, qkvb, qo, ko, vo);
  attn_k<<<dim3(T / 128, B * H), 512, 0, stream>>>(qo, ko, vo, at);
  proj_gemm_k<<<dim3(T / 128, C / 128, B), 256, 0, stream>>>(at, wp, projb, x, out);
}

// Round 4
// 156.730 us; speedup vs baseline: 1.5416x; 1.2334x over previous
//
#include <hip/hip_runtime.h>

typedef short bf16x8 __attribute__((ext_vector_type(8)));
typedef float f32x4 __attribute__((ext_vector_type(4)));
typedef float f32x16 __attribute__((ext_vector_type(16)));
typedef unsigned short u16;
typedef unsigned int u32;

constexpr int B = 4, C = 512, T = 2048, H = 8, G = 32;
constexpr int CH = C / H;   // 64
constexpr int CPG = C / G;  // 16
constexpr float EPS = 1e-5f;
// softmax scale folded into Q: p = exp2(S_raw * 0.125 * log2(e))
constexpr float SCLQ = 0.18033688011112042f;

__device__ __forceinline__ u16 f2bf(float f) {
  union { float f; u32 u; } v; v.f = f;
  return (u16)((v.u + 0x7FFFu + ((v.u >> 16) & 1u)) >> 16);
}

__device__ __forceinline__ void gload16(const void* g, void* lds) {
  __builtin_amdgcn_global_load_lds(
      (const __attribute__((address_space(1))) void*)g,
      (__attribute__((address_space(3))) void*)lds, 16, 0, 0);
}

// XOR-swizzled staging: ROWS x 64 bf16 tile -> linear LDS [ROWS][64].
// Global source column pre-swizzled; reads apply col ^ ((row&7)<<3).
template <int ROWS>  // 256-thread blocks
__device__ __forceinline__ void stage_swz_4w(u16* lds, const u16* gsrc, int ldk) {
  const int tid = threadIdx.x;
  const int w = tid >> 6, lane = tid & 63;
#pragma unroll
  for (int i = 0; i < ROWS / 32; ++i) {
    const int chunk = i * 4 + w;                 // 1KB chunk = 8 rows of 128B
    const int row = chunk * 8 + (lane >> 3);
    const int col = ((lane & 7) * 8) ^ ((row & 7) << 3);
    gload16(gsrc + (size_t)row * ldk + col, (char*)lds + chunk * 1024);
  }
}

// ---------------- GroupNorm ----------------
__global__ __launch_bounds__(256) void gn_stats_k(const float* __restrict__ x,
                                                  float* __restrict__ stats) {
  const int bg = blockIdx.x;
  const float4* xp = (const float4*)(x + (size_t)bg * CPG * T);
  float s = 0.f, ss = 0.f;
  for (int i = threadIdx.x; i < CPG * T / 4; i += 256) {
    float4 v = xp[i];
    s += v.x + v.y + v.z + v.w;
    ss += v.x * v.x + v.y * v.y + v.z * v.z + v.w * v.w;
  }
  for (int off = 32; off; off >>= 1) {
    s += __shfl_down(s, off);
    ss += __shfl_down(ss, off);
  }
  __shared__ float red[8];
  const int w = threadIdx.x >> 6;
  if ((threadIdx.x & 63) == 0) { red[w] = s; red[4 + w] = ss; }
  __syncthreads();
  if (threadIdx.x == 0) {
    float S = red[0] + red[1] + red[2] + red[3];
    float SS = red[4] + red[5] + red[6] + red[7];
    const float inv = 1.f / (float)(CPG * T);
    float mean = S * inv;
    float var = SS * inv - mean * mean;
    stats[bg * 2] = mean;
    stats[bg * 2 + 1] = rsqrtf(var + EPS);
  }
}

__global__ __launch_bounds__(256) void gn_apply_k(const float* __restrict__ x,
                                                  const float* __restrict__ stats,
                                                  const float* __restrict__ gsc,
                                                  const float* __restrict__ gbi,
                                                  u16* __restrict__ ht) {
  const int b = blockIdx.y;
  const int t0 = blockIdx.x * 32;
#pragma unroll
  for (int p = 0; p < 2; ++p) {
    const int c = p * 256 + threadIdx.x;
    const int bg = b * G + (c >> 4);
    const float mean = stats[bg * 2], rstd = stats[bg * 2 + 1];
    const float sc = gsc[c] * rstd;
    const float bi = gbi[c] - mean * sc;
    const float4* xp = (const float4*)(x + ((size_t)b * C + c) * T + t0);
#pragma unroll
    for (int j = 0; j < 8; ++j) {
      float4 v = xp[j];
      const int t = t0 + j * 4;
      u16* hp = ht + ((size_t)b * T + t) * C + c;
      hp[0]     = f2bf(v.x * sc + bi);
      hp[C]     = f2bf(v.y * sc + bi);
      hp[2 * C] = f2bf(v.z * sc + bi);
      hp[3 * C] = f2bf(v.w * sc + bi);
    }
  }
}

// ---------------- fp32 -> bf16 weight cast ----------------
__global__ __launch_bounds__(256) void cast_bf_k(const float* __restrict__ src,
                                                 u16* __restrict__ dst, int n4) {
  int i = blockIdx.x * 256 + threadIdx.x;
  if (i < n4) {
    float4 v = ((const float4*)src)[i];
    uint2 pk;
    pk.x = (u32)f2bf(v.x) | ((u32)f2bf(v.y) << 16);
    pk.y = (u32)f2bf(v.z) | ((u32)f2bf(v.w) << 16);
    ((uint2*)dst)[i] = pk;
  }
}

// ---------------- QKV bt-GEMM: C'[t][o] = sum_c h_t[t][c] * W[o][c] ----------------
__global__ __launch_bounds__(256) void qkv_gemm_k(const u16* __restrict__ ht,
                                                  const u16* __restrict__ wq,
                                                  const float* __restrict__ qkvb,
                                                  u16* __restrict__ qo,
                                                  u16* __restrict__ kvo_k,
                                                  u16* __restrict__ kvo_v) {
  __shared__ u16 As[128 * 64];
  __shared__ u16 Bs[128 * 64];
  const int mt = blockIdx.x, nt = blockIdx.y, b = blockIdx.z;
  const u16* Ab = ht + ((size_t)b * T + mt * 128) * C;
  const u16* Bb = wq + (size_t)nt * 128 * C;
  const int tid = threadIdx.x, lane = tid & 63, w = tid >> 6;
  const int wr = w >> 1, wc = w & 1, l15 = lane & 15, lhi = lane >> 4;
  const int swz = (l15 & 7) << 3;

  const f32x4 vzero = {0.f, 0.f, 0.f, 0.f};
  f32x4 acc[4][4];
#pragma unroll
  for (int m = 0; m < 4; ++m)
#pragma unroll
    for (int n = 0; n < 4; ++n) acc[m][n] = vzero;

  for (int kt = 0; kt < C / 64; ++kt) {
    stage_swz_4w<128>(As, Ab + kt * 64, C);
    stage_swz_4w<128>(Bs, Bb + kt * 64, C);
    __syncthreads();
#pragma unroll
    for (int kk = 0; kk < 2; ++kk) {
      const int koff = (kk * 32 + lhi * 8) ^ swz;
      bf16x8 af[4], bfv[4];
#pragma unroll
      for (int m = 0; m < 4; ++m)
        af[m] = *(const bf16x8*)&As[(wr * 64 + m * 16 + l15) * 64 + koff];
#pragma unroll
      for (int n = 0; n < 4; ++n)
        bfv[n] = *(const bf16x8*)&Bs[(wc * 64 + n * 16 + l15) * 64 + koff];
#pragma unroll
      for (int m = 0; m < 4; ++m)
#pragma unroll
        for (int n = 0; n < 4; ++n)
          acc[m][n] = __builtin_amdgcn_mfma_f32_16x16x32_bf16(af[m], bfv[n], acc[m][n], 0, 0, 0);
    }
    __syncthreads();
  }
#pragma unroll
  for (int n = 0; n < 4; ++n) {
    const int o = nt * 128 + wc * 64 + n * 16 + l15;
    const float bias = qkvb[o];
    const int which = o >> 9, rem = o & 511, hh = rem >> 6, d = rem & 63;
    const size_t bh = (size_t)b * H + hh;
#pragma unroll
    for (int m = 0; m < 4; ++m) {
      const int tbase = mt * 128 + wr * 64 + m * 16 + lhi * 4;
#pragma unroll
      for (int r = 0; r < 4; ++r) {
        float val = acc[m][n][r] + bias;
        if (which == 0) val *= SCLQ;   // fold softmax scale into Q
        const u16 bv = f2bf(val);
        const int t = tbase + r;
        if (which == 0)      qo[(bh * T + t) * CH + d] = bv;
        else if (which == 1) kvo_k[(bh * T + t) * CH + d] = bv;
        else                 kvo_v[(bh * CH + d) * T + t] = bv;
      }
    }
  }
}

// ---------------- flash attention: 4 waves x 32 q-rows, 32x32x16 MFMA,
// swapped QK^T, in-register no-max softmax, P never touches LDS ----------------
__global__ __launch_bounds__(256) void attn_k(const u16* __restrict__ q,
                                              const u16* __restrict__ k,
                                              const u16* __restrict__ v,
                                              u16* __restrict__ at) {
  __shared__ u16 Qs[128 * 64];
  __shared__ u16 Ks[2][64 * 64];
  __shared__ u16 Vs[2][64 * 64];
  const int qt = blockIdx.x, bh = blockIdx.y;
  const int tid = threadIdx.x, lane = tid & 63, w = tid >> 6;
  const int l31 = lane & 31, h = lane >> 5;
  const u16* qb = q + (size_t)bh * T * CH;
  const u16* kb = k + (size_t)bh * T * CH;
  const u16* vb = v + (size_t)bh * CH * T;

  stage_swz_4w<128>(Qs, qb + qt * 128 * CH, CH);
  stage_swz_4w<64>(Ks[0], kb, CH);
  stage_swz_4w<64>(Vs[0], vb, T);  // V tile: rows=d(64), cols=s(64)
  __syncthreads();

  // Hoist Q B-frags (wave w owns q-rows w*32..w*32+31; lane col = q = l31)
  bf16x8 qf[4];
  {
    const int qrow = w * 32 + l31;
    const int qswz = (qrow & 7) << 3;
#pragma unroll
    for (int ks = 0; ks < 4; ++ks)
      qf[ks] = *(const bf16x8*)&Qs[qrow * 64 + ((ks * 16 + h * 8) ^ qswz)];
  }

  f32x16 accO0 = {0.f,0.f,0.f,0.f,0.f,0.f,0.f,0.f,0.f,0.f,0.f,0.f,0.f,0.f,0.f,0.f};
  f32x16 accO1 = accO0;
  float lsum = 0.f;
  const int kswz = (l31 & 7) << 3;  // rows kt*32+l31: (row&7)==(l31&7)

  int cur = 0;
  for (int it = 0; it < T / 64; ++it) {
    if (it + 1 < T / 64) {  // prefetch next K/V tile (dbuf)
      stage_swz_4w<64>(Ks[cur ^ 1], kb + (size_t)(it + 1) * 64 * CH, CH);
      stage_swz_4w<64>(Vs[cur ^ 1], vb + (it + 1) * 64, T);
    }
    const u16* Kc = Ks[cur];
    const u16* Vc = Vs[cur];

    // QK^T swapped: accS[kt] = S^T[kv = kt*32 + crow][q = l31]
    f32x16 accS0 = {0.f,0.f,0.f,0.f,0.f,0.f,0.f,0.f,0.f,0.f,0.f,0.f,0.f,0.f,0.f,0.f};
    f32x16 accS1 = accS0;
#pragma unroll
    for (int ks = 0; ks < 4; ++ks) {
      const int col = (ks * 16 + h * 8) ^ kswz;
      bf16x8 kf0 = *(const bf16x8*)&Kc[l31 * 64 + col];
      bf16x8 kf1 = *(const bf16x8*)&Kc[(32 + l31) * 64 + col];
      accS0 = __builtin_amdgcn_mfma_f32_32x32x16_bf16(kf0, qf[ks], accS0, 0, 0, 0);
      accS1 = __builtin_amdgcn_mfma_f32_32x32x16_bf16(kf1, qf[ks], accS1, 0, 0, 0);
    }

    // No-max softmax: p = exp2(S*scl) (scale pre-folded into Q); partial lsum;
    // pack to bf16 pairs (k-adjacent in C/D layout: reg r -> kv=(r&3)+8(r>>2)+4h)
    u32 wd0[8], wd1[8];
#pragma unroll
    for (int i = 0; i < 8; ++i) {
      float pa = exp2f(accS0[2 * i]), pb = exp2f(accS0[2 * i + 1]);
      lsum += pa + pb;
      asm("v_cvt_pk_bf16_f32 %0, %1, %2" : "=v"(wd0[i]) : "v"(pa), "v"(pb));
    }
#pragma unroll
    for (int i = 0; i < 8; ++i) {
      float pa = exp2f(accS1[2 * i]), pb = exp2f(accS1[2 * i + 1]);
      lsum += pa + pb;
      asm("v_cvt_pk_bf16_f32 %0, %1, %2" : "=v"(wd1[i]) : "v"(pa), "v"(pb));
    }

    // PV: build A-frags fully in-register via cross-half word exchange.
    // Lane h holds kv = (r&3)+8*(r>>2)+4h; A-frag wants kv = h*8+j contiguous.
#pragma unroll
    for (int kt = 0; kt < 2; ++kt) {
      const u32* wd = kt ? wd1 : wd0;
      u32 pw[8];
#pragma unroll
      for (int i = 0; i < 8; ++i) pw[i] = __shfl_xor(wd[i], 32);
      union { u32 u[4]; bf16x8 v8; } fa, fb;
      fa.u[0] = h ? pw[2] : wd[0];
      fa.u[1] = h ? pw[3] : wd[1];
      fa.u[2] = h ? wd[2] : pw[0];
      fa.u[3] = h ? wd[3] : pw[1];
      fb.u[0] = h ? pw[6] : wd[4];
      fb.u[1] = h ? pw[7] : wd[5];
      fb.u[2] = h ? wd[6] : pw[4];
      fb.u[3] = h ? wd[7] : pw[5];
      const int sA = (kt * 32 + h * 8) ^ kswz;        // s-chunk kt*2
      const int sB = (kt * 32 + 16 + h * 8) ^ kswz;   // s-chunk kt*2+1
      {
        bf16x8 vf0 = *(const bf16x8*)&Vc[l31 * 64 + sA];
        bf16x8 vf1 = *(const bf16x8*)&Vc[l31 * 64 + sB];
        accO0 = __builtin_amdgcn_mfma_f32_32x32x16_bf16(fa.v8, vf0, accO0, 0, 0, 0);
        accO0 = __builtin_amdgcn_mfma_f32_32x32x16_bf16(fb.v8, vf1, accO0, 0, 0, 0);
      }
      {
        bf16x8 vf0 = *(const bf16x8*)&Vc[(32 + l31) * 64 + sA];
        bf16x8 vf1 = *(const bf16x8*)&Vc[(32 + l31) * 64 + sB];
        accO1 = __builtin_amdgcn_mfma_f32_32x32x16_bf16(fa.v8, vf0, accO1, 0, 0, 0);
        accO1 = __builtin_amdgcn_mfma_f32_32x32x16_bf16(fb.v8, vf1, accO1, 0, 0, 0);
      }
    }
    __syncthreads();  // drains vmcnt: next tile staged, all waves done with cur
    cur ^= 1;
  }

  // lsum: combine lane halves (lanes l and l+32 share q-col l31)
  lsum += __shfl_xor(lsum, 32);
  const float inv = 1.f / lsum;  // inv for q = l31, valid in both halves
  const int bq = bh >> 3, hh = bh & 7;
#pragma unroll
  for (int r = 0; r < 16; ++r) {
    const int qrow = (r & 3) + 8 * (r >> 2) + 4 * h;
    const float invr = __shfl(inv, qrow);  // inv of row-q lives at lane qrow
    const int t = qt * 128 + w * 32 + qrow;
    const int c0 = hh * 64 + l31;
    u16* op = at + ((size_t)bq * T + t) * C + c0;
    op[0]  = f2bf(accO0[r] * invr);
    op[32] = f2bf(accO1[r] * invr);
  }
}

// ---------------- proj bt-GEMM + bias + residual ----------------
__global__ __launch_bounds__(256) void proj_gemm_k(const u16* __restrict__ at,
                                                   const u16* __restrict__ wp,
                                                   const float* __restrict__ pb,
                                                   const float* __restrict__ x,
                                                   float* __restrict__ out) {
  __shared__ u16 As[128 * 64];
  __shared__ u16 Bs[128 * 64];
  const int mt = blockIdx.x, nt = blockIdx.y, b = blockIdx.z;
  const u16* Ab = at + ((size_t)b * T + mt * 128) * C;
  const u16* Bb = wp + (size_t)nt * 128 * C;
  const int tid = threadIdx.x, lane = tid & 63, w = tid >> 6;
  const int wr = w >> 1, wc = w & 1, l15 = lane & 15, lhi = lane >> 4;
  const int swz = (l15 & 7) << 3;

  const f32x4 vzero = {0.f, 0.f, 0.f, 0.f};
  f32x4 acc[4][4];
#pragma unroll
  for (int m = 0; m < 4; ++m)
#pragma unroll
    for (int n = 0; n < 4; ++n) acc[m][n] = vzero;

  for (int kt = 0; kt < C / 64; ++kt) {
    stage_swz_4w<128>(As, Ab + kt * 64, C);
    stage_swz_4w<128>(Bs, Bb + kt * 64, C);
    __syncthreads();
#pragma unroll
    for (int kk = 0; kk < 2; ++kk) {
      const int koff = (kk * 32 + lhi * 8) ^ swz;
      bf16x8 af[4], bfv[4];
#pragma unroll
      for (int m = 0; m < 4; ++m)
        af[m] = *(const bf16x8*)&As[(wr * 64 + m * 16 + l15) * 64 + koff];
#pragma unroll
      for (int n = 0; n < 4; ++n)
        bfv[n] = *(const bf16x8*)&Bs[(wc * 64 + n * 16 + l15) * 64 + koff];
#pragma unroll
      for (int m = 0; m < 4; ++m)
#pragma unroll
        for (int n = 0; n < 4; ++n)
          acc[m][n] = __builtin_amdgcn_mfma_f32_16x16x32_bf16(af[m], bfv[n], acc[m][n], 0, 0, 0);
    }
    __syncthreads();
  }
#pragma unroll
  for (int n = 0; n < 4; ++n) {
    const int o = nt * 128 + wc * 64 + n * 16 + l15;
    const float bias = pb[o];
#pragma unroll
    for (int m = 0; m < 4; ++m) {
      const int tbase = mt * 128 + wr * 64 + m * 16 + lhi * 4;
#pragma unroll
      for (int r = 0; r < 4; ++r) {
        const int t = tbase + r;
        const size_t idx = ((size_t)b * C + o) * T + t;
        out[idx] = x[idx] + acc[m][n][r] + bias;
      }
    }
  }
}

extern "C" void kernel_launch(void* const* d_in, const int* in_sizes, int n_in,
                              void* d_out, int out_size, void* d_ws, size_t ws_size,
                              hipStream_t stream) {
  const float* x     = (const float*)d_in[0];
  const float* gsc   = (const float*)d_in[1];
  const float* gbi   = (const float*)d_in[2];
  const float* qkvw  = (const float*)d_in[3];
  const float* qkvb  = (const float*)d_in[4];
  const float* projw = (const float*)d_in[5];
  const float* projb = (const float*)d_in[6];
  float* out = (float*)d_out;

  char* ws = (char*)d_ws;
  float* stats = (float*)ws;
  u16* wq = (u16*)(ws + 1024);
  u16* wp = (u16*)(ws + 1024 + 1572864);
  u16* ht = (u16*)(ws + 2098176);
  u16* qo = (u16*)(ws + 10486784);
  u16* ko = (u16*)(ws + 18875392);
  u16* vo = (u16*)(ws + 27264000);
  u16* at = ht;  // reuse: ht dead after qkv_gemm

  cast_bf_k<<<768, 256, 0, stream>>>(qkvw, wq, 196608);
  cast_bf_k<<<256, 256, 0, stream>>>(projw, wp, 65536);
  gn_stats_k<<<B * G, 256, 0, stream>>>(x, stats);
  gn_apply_k<<<dim3(T / 32, B), 256, 0, stream>>>(x, stats, gsc, gbi, ht);
  qkv_gemm_k<<<dim3(T / 128, (3 * C) / 128, B), 256, 0, stream>>>(ht, wq, qkvb, qo, ko, vo);
  attn_k<<<dim3(T / 128, B * H), 256, 0, stream>>>(qo, ko, vo, at);
  proj_gemm_k<<<dim3(T / 128, C / 128, B), 256, 0, stream>>>(at, wp, projb, x, out);
}

// Round 5
// 150.063 us; speedup vs baseline: 1.6101x; 1.0444x over previous
//
#include <hip/hip_runtime.h>

typedef short bf16x8 __attribute__((ext_vector_type(8)));
typedef float f32x4 __attribute__((ext_vector_type(4)));
typedef float f32x16 __attribute__((ext_vector_type(16)));
typedef unsigned short u16;
typedef unsigned int u32;

constexpr int B = 4, C = 512, T = 2048, H = 8, G = 32;
constexpr int CH = C / H;   // 64
constexpr int CPG = C / G;  // 16
constexpr float EPS = 1e-5f;
// softmax scale folded into Q: p = exp2(S_raw * 0.125 * log2(e))
constexpr float SCLQ = 0.18033688011112042f;

__device__ __forceinline__ u16 f2bf(float f) {
  union { float f; u32 u; } v; v.f = f;
  return (u16)((v.u + 0x7FFFu + ((v.u >> 16) & 1u)) >> 16);
}

__device__ __forceinline__ void gload16(const void* g, void* lds) {
  __builtin_amdgcn_global_load_lds(
      (const __attribute__((address_space(1))) void*)g,
      (__attribute__((address_space(3))) void*)lds, 16, 0, 0);
}

// v_permlane32_swap_b32: a.hi <-> b.lo (exactly the cross-half exchange the
// PV A-fragment needs; replaces ds_bpermute + cndmask, and is VALU not DS pipe)
__device__ __forceinline__ void pl32swap(u32& a, u32& b) {
  asm("v_permlane32_swap_b32 %0, %1" : "+v"(a), "+v"(b));
}

// XOR-swizzled staging: ROWS x 64 bf16 tile -> linear LDS [ROWS][64].
// Global source column pre-swizzled; reads apply col ^ ((row&7)<<3).
template <int ROWS>  // 256-thread blocks
__device__ __forceinline__ void stage_swz_4w(u16* lds, const u16* gsrc, int ldk) {
  const int tid = threadIdx.x;
  const int w = tid >> 6, lane = tid & 63;
#pragma unroll
  for (int i = 0; i < ROWS / 32; ++i) {
    const int chunk = i * 4 + w;                 // 1KB chunk = 8 rows of 128B
    const int row = chunk * 8 + (lane >> 3);
    const int col = ((lane & 7) * 8) ^ ((row & 7) << 3);
    gload16(gsrc + (size_t)row * ldk + col, (char*)lds + chunk * 1024);
  }
}

// ---------------- GroupNorm ----------------
__global__ __launch_bounds__(256) void gn_stats_k(const float* __restrict__ x,
                                                  float* __restrict__ stats) {
  const int bg = blockIdx.x;
  const float4* xp = (const float4*)(x + (size_t)bg * CPG * T);
  float s = 0.f, ss = 0.f;
  for (int i = threadIdx.x; i < CPG * T / 4; i += 256) {
    float4 v = xp[i];
    s += v.x + v.y + v.z + v.w;
    ss += v.x * v.x + v.y * v.y + v.z * v.z + v.w * v.w;
  }
  for (int off = 32; off; off >>= 1) {
    s += __shfl_down(s, off);
    ss += __shfl_down(ss, off);
  }
  __shared__ float red[8];
  const int w = threadIdx.x >> 6;
  if ((threadIdx.x & 63) == 0) { red[w] = s; red[4 + w] = ss; }
  __syncthreads();
  if (threadIdx.x == 0) {
    float S = red[0] + red[1] + red[2] + red[3];
    float SS = red[4] + red[5] + red[6] + red[7];
    const float inv = 1.f / (float)(CPG * T);
    float mean = S * inv;
    float var = SS * inv - mean * mean;
    stats[bg * 2] = mean;
    stats[bg * 2 + 1] = rsqrtf(var + EPS);
  }
}

__global__ __launch_bounds__(256) void gn_apply_k(const float* __restrict__ x,
                                                  const float* __restrict__ stats,
                                                  const float* __restrict__ gsc,
                                                  const float* __restrict__ gbi,
                                                  u16* __restrict__ ht) {
  const int b = blockIdx.y;
  const int t0 = blockIdx.x * 32;
#pragma unroll
  for (int p = 0; p < 2; ++p) {
    const int c = p * 256 + threadIdx.x;
    const int bg = b * G + (c >> 4);
    const float mean = stats[bg * 2], rstd = stats[bg * 2 + 1];
    const float sc = gsc[c] * rstd;
    const float bi = gbi[c] - mean * sc;
    const float4* xp = (const float4*)(x + ((size_t)b * C + c) * T + t0);
#pragma unroll
    for (int j = 0; j < 8; ++j) {
      float4 v = xp[j];
      const int t = t0 + j * 4;
      u16* hp = ht + ((size_t)b * T + t) * C + c;
      hp[0]     = f2bf(v.x * sc + bi);
      hp[C]     = f2bf(v.y * sc + bi);
      hp[2 * C] = f2bf(v.z * sc + bi);
      hp[3 * C] = f2bf(v.w * sc + bi);
    }
  }
}

// ---------------- fp32 -> bf16 weight cast ----------------
__global__ __launch_bounds__(256) void cast_bf_k(const float* __restrict__ src,
                                                 u16* __restrict__ dst, int n4) {
  int i = blockIdx.x * 256 + threadIdx.x;
  if (i < n4) {
    float4 v = ((const float4*)src)[i];
    uint2 pk;
    pk.x = (u32)f2bf(v.x) | ((u32)f2bf(v.y) << 16);
    pk.y = (u32)f2bf(v.z) | ((u32)f2bf(v.w) << 16);
    ((uint2*)dst)[i] = pk;
  }
}

// ---------------- QKV bt-GEMM: C'[t][o] = sum_c h_t[t][c] * W[o][c] ----------------
__global__ __launch_bounds__(256) void qkv_gemm_k(const u16* __restrict__ ht,
                                                  const u16* __restrict__ wq,
                                                  const float* __restrict__ qkvb,
                                                  u16* __restrict__ qo,
                                                  u16* __restrict__ kvo_k,
                                                  u16* __restrict__ kvo_v) {
  __shared__ u16 As[128 * 64];
  __shared__ u16 Bs[128 * 64];
  const int mt = blockIdx.x, nt = blockIdx.y, b = blockIdx.z;
  const u16* Ab = ht + ((size_t)b * T + mt * 128) * C;
  const u16* Bb = wq + (size_t)nt * 128 * C;
  const int tid = threadIdx.x, lane = tid & 63, w = tid >> 6;
  const int wr = w >> 1, wc = w & 1, l15 = lane & 15, lhi = lane >> 4;
  const int swz = (l15 & 7) << 3;

  const f32x4 vzero = {0.f, 0.f, 0.f, 0.f};
  f32x4 acc[4][4];
#pragma unroll
  for (int m = 0; m < 4; ++m)
#pragma unroll
    for (int n = 0; n < 4; ++n) acc[m][n] = vzero;

  for (int kt = 0; kt < C / 64; ++kt) {
    stage_swz_4w<128>(As, Ab + kt * 64, C);
    stage_swz_4w<128>(Bs, Bb + kt * 64, C);
    __syncthreads();
#pragma unroll
    for (int kk = 0; kk < 2; ++kk) {
      const int koff = (kk * 32 + lhi * 8) ^ swz;
      bf16x8 af[4], bfv[4];
#pragma unroll
      for (int m = 0; m < 4; ++m)
        af[m] = *(const bf16x8*)&As[(wr * 64 + m * 16 + l15) * 64 + koff];
#pragma unroll
      for (int n = 0; n < 4; ++n)
        bfv[n] = *(const bf16x8*)&Bs[(wc * 64 + n * 16 + l15) * 64 + koff];
#pragma unroll
      for (int m = 0; m < 4; ++m)
#pragma unroll
        for (int n = 0; n < 4; ++n)
          acc[m][n] = __builtin_amdgcn_mfma_f32_16x16x32_bf16(af[m], bfv[n], acc[m][n], 0, 0, 0);
    }
    __syncthreads();
  }
#pragma unroll
  for (int n = 0; n < 4; ++n) {
    const int o = nt * 128 + wc * 64 + n * 16 + l15;
    const float bias = qkvb[o];
    const int which = o >> 9, rem = o & 511, hh = rem >> 6, d = rem & 63;
    const size_t bh = (size_t)b * H + hh;
#pragma unroll
    for (int m = 0; m < 4; ++m) {
      const int tbase = mt * 128 + wr * 64 + m * 16 + lhi * 4;
#pragma unroll
      for (int r = 0; r < 4; ++r) {
        float val = acc[m][n][r] + bias;
        if (which == 0) val *= SCLQ;   // fold softmax scale into Q
        const u16 bv = f2bf(val);
        const int t = tbase + r;
        if (which == 0)      qo[(bh * T + t) * CH + d] = bv;
        else if (which == 1) kvo_k[(bh * T + t) * CH + d] = bv;
        else                 kvo_v[(bh * CH + d) * T + t] = bv;
      }
    }
  }
}

// ---------------- flash attention: 4 waves x 32 q-rows, 32x32x16 MFMA,
// swapped QK^T, in-register softmax, triple-buffered K/V with counted vmcnt
// (T3/T4: loads stay in flight across s_barrier; never drain in main loop) ---
__global__ __launch_bounds__(256) void attn_k(const u16* __restrict__ q,
                                              const u16* __restrict__ k,
                                              const u16* __restrict__ v,
                                              u16* __restrict__ at) {
  __shared__ u16 Qs[128 * 64];
  __shared__ u16 Ks[3][64 * 64];
  __shared__ u16 Vs[3][64 * 64];
  const int qt = blockIdx.x, bh = blockIdx.y;
  const int tid = threadIdx.x, lane = tid & 63, w = tid >> 6;
  const int l31 = lane & 31, h = lane >> 5;
  const u16* qb = q + (size_t)bh * T * CH;
  const u16* kb = k + (size_t)bh * T * CH;
  const u16* vb = v + (size_t)bh * CH * T;
  constexpr int NT = T / 64;

  // prologue: Q (4 loads/thread), tile0 (4), tile1 (4)
  stage_swz_4w<128>(Qs, qb + qt * 128 * CH, CH);
  stage_swz_4w<64>(Ks[0], kb, CH);
  stage_swz_4w<64>(Vs[0], vb, T);  // V tile: rows=d(64), cols=s(64)
  stage_swz_4w<64>(Ks[1], kb + (size_t)64 * CH, CH);
  stage_swz_4w<64>(Vs[1], vb + 64, T);
  asm volatile("s_waitcnt vmcnt(4)" ::: "memory");  // Q + tile0 landed; tile1 in flight
  __builtin_amdgcn_s_barrier();
  asm volatile("" ::: "memory");

  // Hoist Q B-frags (wave w owns q-rows w*32..w*32+31; lane col = q = l31)
  bf16x8 qf[4];
  {
    const int qrow = w * 32 + l31;
    const int qswz = (qrow & 7) << 3;
#pragma unroll
    for (int ks = 0; ks < 4; ++ks)
      qf[ks] = *(const bf16x8*)&Qs[qrow * 64 + ((ks * 16 + h * 8) ^ qswz)];
  }

  f32x16 accO0 = {0.f,0.f,0.f,0.f,0.f,0.f,0.f,0.f,0.f,0.f,0.f,0.f,0.f,0.f,0.f,0.f};
  f32x16 accO1 = accO0;
  float lsum = 0.f;
  const int kswz = (l31 & 7) << 3;

  int i0 = 0, i1 = 1, i2 = 2;  // cur / next / free slot
  for (int it = 0; it < NT; ++it) {
    // issue prefetch of tile it+2 into the free slot (4 loads; overwrites the
    // buffer everyone finished reading before the PREVIOUS barrier)
    if (it + 2 < NT) {
      stage_swz_4w<64>(Ks[i2], kb + (size_t)(it + 2) * 64 * CH, CH);
      stage_swz_4w<64>(Vs[i2], vb + (it + 2) * 64, T);
    }
    const u16* Kc = Ks[i0];
    const u16* Vc = Vs[i0];

    // QK^T swapped: accS = S^T[kv][q = l31]
    f32x16 accS0 = {0.f,0.f,0.f,0.f,0.f,0.f,0.f,0.f,0.f,0.f,0.f,0.f,0.f,0.f,0.f,0.f};
    f32x16 accS1 = accS0;
    __builtin_amdgcn_s_setprio(1);
#pragma unroll
    for (int ks = 0; ks < 4; ++ks) {
      const int col = (ks * 16 + h * 8) ^ kswz;
      bf16x8 kf0 = *(const bf16x8*)&Kc[l31 * 64 + col];
      bf16x8 kf1 = *(const bf16x8*)&Kc[(32 + l31) * 64 + col];
      accS0 = __builtin_amdgcn_mfma_f32_32x32x16_bf16(kf0, qf[ks], accS0, 0, 0, 0);
      accS1 = __builtin_amdgcn_mfma_f32_32x32x16_bf16(kf1, qf[ks], accS1, 0, 0, 0);
    }
    __builtin_amdgcn_s_setprio(0);

    // No-max softmax: p = exp2(S) (scale pre-folded into Q); partial lsum;
    // pack to bf16 pairs (k-adjacent in C/D layout: reg r -> kv=(r&3)+8(r>>2)+4h)
    u32 wd0[8], wd1[8];
#pragma unroll
    for (int i = 0; i < 8; ++i) {
      float pa = exp2f(accS0[2 * i]), pb = exp2f(accS0[2 * i + 1]);
      lsum += pa + pb;
      asm("v_cvt_pk_bf16_f32 %0, %1, %2" : "=v"(wd0[i]) : "v"(pa), "v"(pb));
    }
#pragma unroll
    for (int i = 0; i < 8; ++i) {
      float pa = exp2f(accS1[2 * i]), pb = exp2f(accS1[2 * i + 1]);
      lsum += pa + pb;
      asm("v_cvt_pk_bf16_f32 %0, %1, %2" : "=v"(wd1[i]) : "v"(pa), "v"(pb));
    }
    // cross-half exchange in-register: after swap, wd[0..3] IS the A-frag for
    // k-chunk 0..15 and wd[4..7] for 16..31 (dst.hi<->src.lo semantics)
    pl32swap(wd0[0], wd0[2]); pl32swap(wd0[1], wd0[3]);
    pl32swap(wd0[4], wd0[6]); pl32swap(wd0[5], wd0[7]);
    pl32swap(wd1[0], wd1[2]); pl32swap(wd1[1], wd1[3]);
    pl32swap(wd1[4], wd1[6]); pl32swap(wd1[5], wd1[7]);

    // PV: O[q][d] += P^T[q][s] * V^T[s][d] (V staged bt-form [d][s])
    __builtin_amdgcn_s_setprio(1);
#pragma unroll
    for (int kt = 0; kt < 2; ++kt) {
      const u32* wd = kt ? wd1 : wd0;
      union { u32 u[4]; bf16x8 v8; } fa, fb;
      fa.u[0] = wd[0]; fa.u[1] = wd[1]; fa.u[2] = wd[2]; fa.u[3] = wd[3];
      fb.u[0] = wd[4]; fb.u[1] = wd[5]; fb.u[2] = wd[6]; fb.u[3] = wd[7];
      const int sA = (kt * 32 + h * 8) ^ kswz;
      const int sB = (kt * 32 + 16 + h * 8) ^ kswz;
      {
        bf16x8 vf0 = *(const bf16x8*)&Vc[l31 * 64 + sA];
        bf16x8 vf1 = *(const bf16x8*)&Vc[l31 * 64 + sB];
        accO0 = __builtin_amdgcn_mfma_f32_32x32x16_bf16(fa.v8, vf0, accO0, 0, 0, 0);
        accO0 = __builtin_amdgcn_mfma_f32_32x32x16_bf16(fb.v8, vf1, accO0, 0, 0, 0);
      }
      {
        bf16x8 vf0 = *(const bf16x8*)&Vc[(32 + l31) * 64 + sA];
        bf16x8 vf1 = *(const bf16x8*)&Vc[(32 + l31) * 64 + sB];
        accO1 = __builtin_amdgcn_mfma_f32_32x32x16_bf16(fa.v8, vf0, accO1, 0, 0, 0);
        accO1 = __builtin_amdgcn_mfma_f32_32x32x16_bf16(fb.v8, vf1, accO1, 0, 0, 0);
      }
    }
    __builtin_amdgcn_s_setprio(0);

    // counted wait (T4): keep newest 4 (tile it+2's stage) in flight across
    // the barrier; drains tile it+1's writes -> readable next iter.
    if (it + 2 < NT) asm volatile("s_waitcnt vmcnt(4)" ::: "memory");
    else             asm volatile("s_waitcnt vmcnt(0)" ::: "memory");
    __builtin_amdgcn_s_barrier();
    asm volatile("" ::: "memory");
    const int tmp = i0; i0 = i1; i1 = i2; i2 = tmp;
  }

  // lsum: combine lane halves (lanes l and l+32 share q-col l31)
  lsum += __shfl_xor(lsum, 32);
  const float inv = 1.f / lsum;
  const int bq = bh >> 3, hh = bh & 7;
#pragma unroll
  for (int r = 0; r < 16; ++r) {
    const int qrow = (r & 3) + 8 * (r >> 2) + 4 * h;
    const float invr = __shfl(inv, qrow);  // inv of row-q lives at lane qrow
    const int t = qt * 128 + w * 32 + qrow;
    const int c0 = hh * 64 + l31;
    u16* op = at + ((size_t)bq * T + t) * C + c0;
    op[0]  = f2bf(accO0[r] * invr);
    op[32] = f2bf(accO1[r] * invr);
  }
}

// ---------------- proj bt-GEMM + bias + residual ----------------
__global__ __launch_bounds__(256) void proj_gemm_k(const u16* __restrict__ at,
                                                   const u16* __restrict__ wp,
                                                   const float* __restrict__ pb,
                                                   const float* __restrict__ x,
                                                   float* __restrict__ out) {
  __shared__ u16 As[128 * 64];
  __shared__ u16 Bs[128 * 64];
  const int mt = blockIdx.x, nt = blockIdx.y, b = blockIdx.z;
  const u16* Ab = at + ((size_t)b * T + mt * 128) * C;
  const u16* Bb = wp + (size_t)nt * 128 * C;
  const int tid = threadIdx.x, lane = tid & 63, w = tid >> 6;
  const int wr = w >> 1, wc = w & 1, l15 = lane & 15, lhi = lane >> 4;
  const int swz = (l15 & 7) << 3;

  const f32x4 vzero = {0.f, 0.f, 0.f, 0.f};
  f32x4 acc[4][4];
#pragma unroll
  for (int m = 0; m < 4; ++m)
#pragma unroll
    for (int n = 0; n < 4; ++n) acc[m][n] = vzero;

  for (int kt = 0; kt < C / 64; ++kt) {
    stage_swz_4w<128>(As, Ab + kt * 64, C);
    stage_swz_4w<128>(Bs, Bb + kt * 64, C);
    __syncthreads();
#pragma unroll
    for (int kk = 0; kk < 2; ++kk) {
      const int koff = (kk * 32 + lhi * 8) ^ swz;
      bf16x8 af[4], bfv[4];
#pragma unroll
      for (int m = 0; m < 4; ++m)
        af[m] = *(const bf16x8*)&As[(wr * 64 + m * 16 + l15) * 64 + koff];
#pragma unroll
      for (int n = 0; n < 4; ++n)
        bfv[n] = *(const bf16x8*)&Bs[(wc * 64 + n * 16 + l15) * 64 + koff];
#pragma unroll
      for (int m = 0; m < 4; ++m)
#pragma unroll
        for (int n = 0; n < 4; ++n)
          acc[m][n] = __builtin_amdgcn_mfma_f32_16x16x32_bf16(af[m], bfv[n], acc[m][n], 0, 0, 0);
    }
    __syncthreads();
  }
#pragma unroll
  for (int n = 0; n < 4; ++n) {
    const int o = nt * 128 + wc * 64 + n * 16 + l15;
    const float bias = pb[o];
#pragma unroll
    for (int m = 0; m < 4; ++m) {
      const int tbase = mt * 128 + wr * 64 + m * 16 + lhi * 4;
#pragma unroll
      for (int r = 0; r < 4; ++r) {
        const int t = tbase + r;
        const size_t idx = ((size_t)b * C + o) * T + t;
        out[idx] = x[idx] + acc[m][n][r] + bias;
      }
    }
  }
}

extern "C" void kernel_launch(void* const* d_in, const int* in_sizes, int n_in,
                              void* d_out, int out_size, void* d_ws, size_t ws_size,
                              hipStream_t stream) {
  const float* x     = (const float*)d_in[0];
  const float* gsc   = (const float*)d_in[1];
  const float* gbi   = (const float*)d_in[2];
  const float* qkvw  = (const float*)d_in[3];
  const float* qkvb  = (const float*)d_in[4];
  const float* projw = (const float*)d_in[5];
  const float* projb = (const float*)d_in[6];
  float* out = (float*)d_out;

  char* ws = (char*)d_ws;
  float* stats = (float*)ws;
  u16* wq = (u16*)(ws + 1024);
  u16* wp = (u16*)(ws + 1024 + 1572864);
  u16* ht = (u16*)(ws + 2098176);
  u16* qo = (u16*)(ws + 10486784);
  u16* ko = (u16*)(ws + 18875392);
  u16* vo = (u16*)(ws + 27264000);
  u16* at = ht;  // reuse: ht dead after qkv_gemm

  cast_bf_k<<<768, 256, 0, stream>>>(qkvw, wq, 196608);
  cast_bf_k<<<256, 256, 0, stream>>>(projw, wp, 65536);
  gn_stats_k<<<B * G, 256, 0, stream>>>(x, stats);
  gn_apply_k<<<dim3(T / 32, B), 256, 0, stream>>>(x, stats, gsc, gbi, ht);
  qkv_gemm_k<<<dim3(T / 128, (3 * C) / 128, B), 256, 0, stream>>>(ht, wq, qkvb, qo, ko, vo);
  attn_k<<<dim3(T / 128, B * H), 256, 0, stream>>>(qo, ko, vo, at);
  proj_gemm_k<<<dim3(T / 128, C / 128, B), 256, 0, stream>>>(at, wp, projb, x, out);
}

// Round 6
// 147.516 us; speedup vs baseline: 1.6379x; 1.0173x over previous
//
#include <hip/hip_runtime.h>

typedef short bf16x8 __attribute__((ext_vector_type(8)));
typedef float f32x4 __attribute__((ext_vector_type(4)));
typedef float f32x16 __attribute__((ext_vector_type(16)));
typedef unsigned short u16;
typedef unsigned int u32;

constexpr int B = 4, C = 512, T = 2048, H = 8, G = 32;
constexpr int CH = C / H;   // 64
constexpr int CPG = C / G;  // 16
constexpr float EPS = 1e-5f;
// softmax scale folded into Q: p = exp2(S_raw * 0.125 * log2(e))
constexpr float SCLQ = 0.18033688011112042f;

__device__ __forceinline__ u16 f2bf(float f) {
  union { float f; u32 u; } v; v.f = f;
  return (u16)((v.u + 0x7FFFu + ((v.u >> 16) & 1u)) >> 16);
}

__device__ __forceinline__ void gload16(const void* g, void* lds) {
  __builtin_amdgcn_global_load_lds(
      (const __attribute__((address_space(1))) void*)g,
      (__attribute__((address_space(3))) void*)lds, 16, 0, 0);
}

// v_permlane32_swap_b32: a.hi <-> b.lo (cross-half exchange for the PV
// A-fragment; VALU pipe, replaces ds_bpermute + cndmask)
__device__ __forceinline__ void pl32swap(u32& a, u32& b) {
  asm("v_permlane32_swap_b32 %0, %1" : "+v"(a), "+v"(b));
}

// XOR-swizzled staging: ROWS x 64 bf16 tile -> linear LDS [ROWS][64].
// Global source column pre-swizzled; reads apply col ^ ((row&7)<<3).
template <int ROWS>  // 256-thread blocks
__device__ __forceinline__ void stage_swz_4w(u16* lds, const u16* gsrc, int ldk) {
  const int tid = threadIdx.x;
  const int w = tid >> 6, lane = tid & 63;
#pragma unroll
  for (int i = 0; i < ROWS / 32; ++i) {
    const int chunk = i * 4 + w;                 // 1KB chunk = 8 rows of 128B
    const int row = chunk * 8 + (lane >> 3);
    const int col = ((lane & 7) * 8) ^ ((row & 7) << 3);
    gload16(gsrc + (size_t)row * ldk + col, (char*)lds + chunk * 1024);
  }
}

// ---------------- GroupNorm ----------------
__global__ __launch_bounds__(256) void gn_stats_k(const float* __restrict__ x,
                                                  float* __restrict__ stats) {
  const int bg = blockIdx.x;
  const float4* xp = (const float4*)(x + (size_t)bg * CPG * T);
  float s = 0.f, ss = 0.f;
  for (int i = threadIdx.x; i < CPG * T / 4; i += 256) {
    float4 v = xp[i];
    s += v.x + v.y + v.z + v.w;
    ss += v.x * v.x + v.y * v.y + v.z * v.z + v.w * v.w;
  }
  for (int off = 32; off; off >>= 1) {
    s += __shfl_down(s, off);
    ss += __shfl_down(ss, off);
  }
  __shared__ float red[8];
  const int w = threadIdx.x >> 6;
  if ((threadIdx.x & 63) == 0) { red[w] = s; red[4 + w] = ss; }
  __syncthreads();
  if (threadIdx.x == 0) {
    float S = red[0] + red[1] + red[2] + red[3];
    float SS = red[4] + red[5] + red[6] + red[7];
    const float inv = 1.f / (float)(CPG * T);
    float mean = S * inv;
    float var = SS * inv - mean * mean;
    stats[bg * 2] = mean;
    stats[bg * 2 + 1] = rsqrtf(var + EPS);
  }
}

__global__ __launch_bounds__(256) void gn_apply_k(const float* __restrict__ x,
                                                  const float* __restrict__ stats,
                                                  const float* __restrict__ gsc,
                                                  const float* __restrict__ gbi,
                                                  u16* __restrict__ ht) {
  const int b = blockIdx.y;
  const int t0 = blockIdx.x * 32;
#pragma unroll
  for (int p = 0; p < 2; ++p) {
    const int c = p * 256 + threadIdx.x;
    const int bg = b * G + (c >> 4);
    const float mean = stats[bg * 2], rstd = stats[bg * 2 + 1];
    const float sc = gsc[c] * rstd;
    const float bi = gbi[c] - mean * sc;
    const float4* xp = (const float4*)(x + ((size_t)b * C + c) * T + t0);
#pragma unroll
    for (int j = 0; j < 8; ++j) {
      float4 v = xp[j];
      const int t = t0 + j * 4;
      u16* hp = ht + ((size_t)b * T + t) * C + c;
      hp[0]     = f2bf(v.x * sc + bi);
      hp[C]     = f2bf(v.y * sc + bi);
      hp[2 * C] = f2bf(v.z * sc + bi);
      hp[3 * C] = f2bf(v.w * sc + bi);
    }
  }
}

// ---------------- fp32 -> bf16 weight casts (both weights, one launch) ----------------
__global__ __launch_bounds__(256) void cast_bf_k(const float* __restrict__ s1,
                                                 u16* __restrict__ d1, int n1,
                                                 const float* __restrict__ s2,
                                                 u16* __restrict__ d2, int n2) {
  int i = blockIdx.x * 256 + threadIdx.x;
  const float4* src = (const float4*)s1;
  uint2* dst = (uint2*)d1;
  if (i >= n1) { i -= n1; if (i >= n2) return; src = (const float4*)s2; dst = (uint2*)d2; }
  float4 v = src[i];
  uint2 pk;
  pk.x = (u32)f2bf(v.x) | ((u32)f2bf(v.y) << 16);
  pk.y = (u32)f2bf(v.z) | ((u32)f2bf(v.w) << 16);
  dst[i] = pk;
}

// ---------------- QKV bt-GEMM: C'[t][o] = sum_c h_t[t][c] * W[o][c] ----------------
__global__ __launch_bounds__(256) void qkv_gemm_k(const u16* __restrict__ ht,
                                                  const u16* __restrict__ wq,
                                                  const float* __restrict__ qkvb,
                                                  u16* __restrict__ qo,
                                                  u16* __restrict__ kvo_k,
                                                  u16* __restrict__ kvo_v) {
  __shared__ u16 As[128 * 64];
  __shared__ u16 Bs[128 * 64];
  const int mt = blockIdx.x, nt = blockIdx.y, b = blockIdx.z;
  const u16* Ab = ht + ((size_t)b * T + mt * 128) * C;
  const u16* Bb = wq + (size_t)nt * 128 * C;
  const int tid = threadIdx.x, lane = tid & 63, w = tid >> 6;
  const int wr = w >> 1, wc = w & 1, l15 = lane & 15, lhi = lane >> 4;
  const int swz = (l15 & 7) << 3;

  const f32x4 vzero = {0.f, 0.f, 0.f, 0.f};
  f32x4 acc[4][4];
#pragma unroll
  for (int m = 0; m < 4; ++m)
#pragma unroll
    for (int n = 0; n < 4; ++n) acc[m][n] = vzero;

  for (int kt = 0; kt < C / 64; ++kt) {
    stage_swz_4w<128>(As, Ab + kt * 64, C);
    stage_swz_4w<128>(Bs, Bb + kt * 64, C);
    __syncthreads();
#pragma unroll
    for (int kk = 0; kk < 2; ++kk) {
      const int koff = (kk * 32 + lhi * 8) ^ swz;
      bf16x8 af[4], bfv[4];
#pragma unroll
      for (int m = 0; m < 4; ++m)
        af[m] = *(const bf16x8*)&As[(wr * 64 + m * 16 + l15) * 64 + koff];
#pragma unroll
      for (int n = 0; n < 4; ++n)
        bfv[n] = *(const bf16x8*)&Bs[(wc * 64 + n * 16 + l15) * 64 + koff];
#pragma unroll
      for (int m = 0; m < 4; ++m)
#pragma unroll
        for (int n = 0; n < 4; ++n)
          acc[m][n] = __builtin_amdgcn_mfma_f32_16x16x32_bf16(af[m], bfv[n], acc[m][n], 0, 0, 0);
    }
    __syncthreads();
  }
#pragma unroll
  for (int n = 0; n < 4; ++n) {
    const int o = nt * 128 + wc * 64 + n * 16 + l15;
    const float bias = qkvb[o];
    const int which = o >> 9, rem = o & 511, hh = rem >> 6, d = rem & 63;
    const size_t bh = (size_t)b * H + hh;
#pragma unroll
    for (int m = 0; m < 4; ++m) {
      const int tbase = mt * 128 + wr * 64 + m * 16 + lhi * 4;
#pragma unroll
      for (int r = 0; r < 4; ++r) {
        float val = acc[m][n][r] + bias;
        if (which == 0) val *= SCLQ;   // fold softmax scale into Q
        const u16 bv = f2bf(val);
        const int t = tbase + r;
        if (which == 0)      qo[(bh * T + t) * CH + d] = bv;
        else if (which == 1) kvo_k[(bh * T + t) * CH + d] = bv;
        else                 kvo_v[(bh * CH + d) * T + t] = bv;
      }
    }
  }
}

// ---------------- flash attention: 4 waves x 32 q-rows, 32x32x16 MFMA,
// swapped QK^T, in-register softmax. Q lives in registers (no LDS);
// K/V double-buffered (32KB LDS -> 5 blocks/CU for latency hiding). ---------
__global__ __launch_bounds__(256) void attn_k(const u16* __restrict__ q,
                                              const u16* __restrict__ k,
                                              const u16* __restrict__ v,
                                              u16* __restrict__ at) {
  __shared__ u16 Ks[2][64 * 64];
  __shared__ u16 Vs[2][64 * 64];
  const int qt = blockIdx.x, bh = blockIdx.y;
  const int tid = threadIdx.x, lane = tid & 63, w = tid >> 6;
  const int l31 = lane & 31, h = lane >> 5;
  const u16* qb = q + (size_t)bh * T * CH;
  const u16* kb = k + (size_t)bh * T * CH;
  const u16* vb = v + (size_t)bh * CH * T;
  constexpr int NT = T / 64;

  // Q B-frags straight from global (wave w owns q-rows w*32..w*32+31;
  // lane's fragment = 4 x 16B contiguous loads, L2-resident)
  bf16x8 qf[4];
  {
    const u16* qp = qb + (size_t)(qt * 128 + w * 32 + l31) * CH + h * 8;
#pragma unroll
    for (int ks = 0; ks < 4; ++ks) qf[ks] = *(const bf16x8*)(qp + ks * 16);
  }

  // prologue: stage tile 0
  stage_swz_4w<64>(Ks[0], kb, CH);
  stage_swz_4w<64>(Vs[0], vb, T);  // V tile: rows=d(64), cols=s(64)
  asm volatile("s_waitcnt vmcnt(0)" ::: "memory");
  __builtin_amdgcn_s_barrier();
  asm volatile("" ::: "memory");

  f32x16 accO0 = {0.f,0.f,0.f,0.f,0.f,0.f,0.f,0.f,0.f,0.f,0.f,0.f,0.f,0.f,0.f,0.f};
  f32x16 accO1 = accO0;
  float lsum = 0.f;
  const int kswz = (l31 & 7) << 3;

  int cur = 0;
  for (int it = 0; it < NT; ++it) {
    // issue next tile's stage FIRST; its latency hides under this iter's
    // compute, and the buffer it overwrites was released at the last barrier
    if (it + 1 < NT) {
      stage_swz_4w<64>(Ks[cur ^ 1], kb + (size_t)(it + 1) * 64 * CH, CH);
      stage_swz_4w<64>(Vs[cur ^ 1], vb + (it + 1) * 64, T);
    }
    const u16* Kc = Ks[cur];
    const u16* Vc = Vs[cur];

    // QK^T swapped: accS = S^T[kv][q = l31]
    f32x16 accS0 = {0.f,0.f,0.f,0.f,0.f,0.f,0.f,0.f,0.f,0.f,0.f,0.f,0.f,0.f,0.f,0.f};
    f32x16 accS1 = accS0;
    __builtin_amdgcn_s_setprio(1);
#pragma unroll
    for (int ks = 0; ks < 4; ++ks) {
      const int col = (ks * 16 + h * 8) ^ kswz;
      bf16x8 kf0 = *(const bf16x8*)&Kc[l31 * 64 + col];
      bf16x8 kf1 = *(const bf16x8*)&Kc[(32 + l31) * 64 + col];
      accS0 = __builtin_amdgcn_mfma_f32_32x32x16_bf16(kf0, qf[ks], accS0, 0, 0, 0);
      accS1 = __builtin_amdgcn_mfma_f32_32x32x16_bf16(kf1, qf[ks], accS1, 0, 0, 0);
    }
    __builtin_amdgcn_s_setprio(0);

    // No-max softmax: p = exp2(S) (scale pre-folded into Q); partial lsum;
    // pack to bf16 pairs (k-adjacent in C/D layout: reg r -> kv=(r&3)+8(r>>2)+4h)
    u32 wd0[8], wd1[8];
#pragma unroll
    for (int i = 0; i < 8; ++i) {
      float pa = exp2f(accS0[2 * i]), pb = exp2f(accS0[2 * i + 1]);
      lsum += pa + pb;
      asm("v_cvt_pk_bf16_f32 %0, %1, %2" : "=v"(wd0[i]) : "v"(pa), "v"(pb));
    }
#pragma unroll
    for (int i = 0; i < 8; ++i) {
      float pa = exp2f(accS1[2 * i]), pb = exp2f(accS1[2 * i + 1]);
      lsum += pa + pb;
      asm("v_cvt_pk_bf16_f32 %0, %1, %2" : "=v"(wd1[i]) : "v"(pa), "v"(pb));
    }
    // cross-half exchange in-register: after swap, wd[0..3] IS the A-frag for
    // k-chunk 0..15 and wd[4..7] for 16..31 (dst.hi<->src.lo semantics)
    pl32swap(wd0[0], wd0[2]); pl32swap(wd0[1], wd0[3]);
    pl32swap(wd0[4], wd0[6]); pl32swap(wd0[5], wd0[7]);
    pl32swap(wd1[0], wd1[2]); pl32swap(wd1[1], wd1[3]);
    pl32swap(wd1[4], wd1[6]); pl32swap(wd1[5], wd1[7]);

    // PV: O[q][d] += P^T[q][s] * V^T[s][d] (V staged bt-form [d][s])
    __builtin_amdgcn_s_setprio(1);
#pragma unroll
    for (int kt = 0; kt < 2; ++kt) {
      const u32* wd = kt ? wd1 : wd0;
      union { u32 u[4]; bf16x8 v8; } fa, fb;
      fa.u[0] = wd[0]; fa.u[1] = wd[1]; fa.u[2] = wd[2]; fa.u[3] = wd[3];
      fb.u[0] = wd[4]; fb.u[1] = wd[5]; fb.u[2] = wd[6]; fb.u[3] = wd[7];
      const int sA = (kt * 32 + h * 8) ^ kswz;
      const int sB = (kt * 32 + 16 + h * 8) ^ kswz;
      {
        bf16x8 vf0 = *(const bf16x8*)&Vc[l31 * 64 + sA];
        bf16x8 vf1 = *(const bf16x8*)&Vc[l31 * 64 + sB];
        accO0 = __builtin_amdgcn_mfma_f32_32x32x16_bf16(fa.v8, vf0, accO0, 0, 0, 0);
        accO0 = __builtin_amdgcn_mfma_f32_32x32x16_bf16(fb.v8, vf1, accO0, 0, 0, 0);
      }
      {
        bf16x8 vf0 = *(const bf16x8*)&Vc[(32 + l31) * 64 + sA];
        bf16x8 vf1 = *(const bf16x8*)&Vc[(32 + l31) * 64 + sB];
        accO1 = __builtin_amdgcn_mfma_f32_32x32x16_bf16(fa.v8, vf0, accO1, 0, 0, 0);
        accO1 = __builtin_amdgcn_mfma_f32_32x32x16_bf16(fb.v8, vf1, accO1, 0, 0, 0);
      }
    }
    __builtin_amdgcn_s_setprio(0);

    // next tile's loads have had the whole compute phase to land; residual
    // wait is hidden by the other 4 resident blocks (m114 wave overlap)
    asm volatile("s_waitcnt vmcnt(0)" ::: "memory");
    __builtin_amdgcn_s_barrier();
    asm volatile("" ::: "memory");
    cur ^= 1;
  }

  // lsum: combine lane halves (lanes l and l+32 share q-col l31)
  lsum += __shfl_xor(lsum, 32);
  const float inv = 1.f / lsum;
  const int bq = bh >> 3, hh = bh & 7;
#pragma unroll
  for (int r = 0; r < 16; ++r) {
    const int qrow = (r & 3) + 8 * (r >> 2) + 4 * h;
    const float invr = __shfl(inv, qrow);  // inv of row-q lives at lane qrow
    const int t = qt * 128 + w * 32 + qrow;
    const int c0 = hh * 64 + l31;
    u16* op = at + ((size_t)bq * T + t) * C + c0;
    op[0]  = f2bf(accO0[r] * invr);
    op[32] = f2bf(accO1[r] * invr);
  }
}

// ---------------- proj bt-GEMM + bias + residual ----------------
__global__ __launch_bounds__(256) void proj_gemm_k(const u16* __restrict__ at,
                                                   const u16* __restrict__ wp,
                                                   const float* __restrict__ pb,
                                                   const float* __restrict__ x,
                                                   float* __restrict__ out) {
  __shared__ u16 As[128 * 64];
  __shared__ u16 Bs[128 * 64];
  const int mt = blockIdx.x, nt = blockIdx.y, b = blockIdx.z;
  const u16* Ab = at + ((size_t)b * T + mt * 128) * C;
  const u16* Bb = wp + (size_t)nt * 128 * C;
  const int tid = threadIdx.x, lane = tid & 63, w = tid >> 6;
  const int wr = w >> 1, wc = w & 1, l15 = lane & 15, lhi = lane >> 4;
  const int swz = (l15 & 7) << 3;

  const f32x4 vzero = {0.f, 0.f, 0.f, 0.f};
  f32x4 acc[4][4];
#pragma unroll
  for (int m = 0; m < 4; ++m)
#pragma unroll
    for (int n = 0; n < 4; ++n) acc[m][n] = vzero;

  for (int kt = 0; kt < C / 64; ++kt) {
    stage_swz_4w<128>(As, Ab + kt * 64, C);
    stage_swz_4w<128>(Bs, Bb + kt * 64, C);
    __syncthreads();
#pragma unroll
    for (int kk = 0; kk < 2; ++kk) {
      const int koff = (kk * 32 + lhi * 8) ^ swz;
      bf16x8 af[4], bfv[4];
#pragma unroll
      for (int m = 0; m < 4; ++m)
        af[m] = *(const bf16x8*)&As[(wr * 64 + m * 16 + l15) * 64 + koff];
#pragma unroll
      for (int n = 0; n < 4; ++n)
        bfv[n] = *(const bf16x8*)&Bs[(wc * 64 + n * 16 + l15) * 64 + koff];
#pragma unroll
      for (int m = 0; m < 4; ++m)
#pragma unroll
        for (int n = 0; n < 4; ++n)
          acc[m][n] = __builtin_amdgcn_mfma_f32_16x16x32_bf16(af[m], bfv[n], acc[m][n], 0, 0, 0);
    }
    __syncthreads();
  }
#pragma unroll
  for (int n = 0; n < 4; ++n) {
    const int o = nt * 128 + wc * 64 + n * 16 + l15;
    const float bias = pb[o];
#pragma unroll
    for (int m = 0; m < 4; ++m) {
      const int tbase = mt * 128 + wr * 64 + m * 16 + lhi * 4;
#pragma unroll
      for (int r = 0; r < 4; ++r) {
        const int t = tbase + r;
        const size_t idx = ((size_t)b * C + o) * T + t;
        out[idx] = x[idx] + acc[m][n][r] + bias;
      }
    }
  }
}

extern "C" void kernel_launch(void* const* d_in, const int* in_sizes, int n_in,
                              void* d_out, int out_size, void* d_ws, size_t ws_size,
                              hipStream_t stream) {
  const float* x     = (const float*)d_in[0];
  const float* gsc   = (const float*)d_in[1];
  const float* gbi   = (const float*)d_in[2];
  const float* qkvw  = (const float*)d_in[3];
  const float* qkvb  = (const float*)d_in[4];
  const float* projw = (const float*)d_in[5];
  const float* projb = (const float*)d_in[6];
  float* out = (float*)d_out;

  char* ws = (char*)d_ws;
  float* stats = (float*)ws;
  u16* wq = (u16*)(ws + 1024);
  u16* wp = (u16*)(ws + 1024 + 1572864);
  u16* ht = (u16*)(ws + 2098176);
  u16* qo = (u16*)(ws + 10486784);
  u16* ko = (u16*)(ws + 18875392);
  u16* vo = (u16*)(ws + 27264000);
  u16* at = ht;  // reuse: ht dead after qkv_gemm

  cast_bf_k<<<1024, 256, 0, stream>>>(qkvw, wq, 196608, projw, wp, 65536);
  gn_stats_k<<<B * G, 256, 0, stream>>>(x, stats);
  gn_apply_k<<<dim3(T / 32, B), 256, 0, stream>>>(x, stats, gsc, gbi, ht);
  qkv_gemm_k<<<dim3(T / 128, (3 * C) / 128, B), 256, 0, stream>>>(ht, wq, qkvb, qo, ko, vo);
  attn_k<<<dim3(T / 128, B * H), 256, 0, stream>>>(qo, ko, vo, at);
  proj_gemm_k<<<dim3(T / 128, C / 128, B), 256, 0, stream>>>(at, wp, projb, x, out);
}

// Round 7
// 139.769 us; speedup vs baseline: 1.7286x; 1.0554x over previous
//
#include <hip/hip_runtime.h>

typedef short bf16x8 __attribute__((ext_vector_type(8)));
typedef float f32x4 __attribute__((ext_vector_type(4)));
typedef float f32x16 __attribute__((ext_vector_type(16)));
typedef unsigned short u16;
typedef unsigned int u32;

constexpr int B = 4, C = 512, T = 2048, H = 8, G = 32;
constexpr int CH = C / H;   // 64
constexpr int CPG = C / G;  // 16
constexpr float EPS = 1e-5f;
// softmax scale folded into Q: p = exp2(S_raw * 0.125 * log2(e))
constexpr float SCLQ = 0.18033688011112042f;

__device__ __forceinline__ u16 f2bf(float f) {
  union { float f; u32 u; } v; v.f = f;
  return (u16)((v.u + 0x7FFFu + ((v.u >> 16) & 1u)) >> 16);
}

__device__ __forceinline__ void gload16(const void* g, void* lds) {
  __builtin_amdgcn_global_load_lds(
      (const __attribute__((address_space(1))) void*)g,
      (__attribute__((address_space(3))) void*)lds, 16, 0, 0);
}

// v_permlane32_swap_b32: a.hi <-> b.lo (cross-half exchange for the PV
// A-fragment; VALU pipe, replaces ds_bpermute + cndmask)
__device__ __forceinline__ void pl32swap(u32& a, u32& b) {
  asm("v_permlane32_swap_b32 %0, %1" : "+v"(a), "+v"(b));
}

// XOR-swizzled staging: ROWS x 64 bf16 tile -> linear LDS [ROWS][64].
// Global source column pre-swizzled; reads apply col ^ ((row&7)<<3).
template <int ROWS>  // 256-thread blocks
__device__ __forceinline__ void stage_swz_4w(u16* lds, const u16* gsrc, int ldk) {
  const int tid = threadIdx.x;
  const int w = tid >> 6, lane = tid & 63;
#pragma unroll
  for (int i = 0; i < ROWS / 32; ++i) {
    const int chunk = i * 4 + w;                 // 1KB chunk = 8 rows of 128B
    const int row = chunk * 8 + (lane >> 3);
    const int col = ((lane & 7) * 8) ^ ((row & 7) << 3);
    gload16(gsrc + (size_t)row * ldk + col, (char*)lds + chunk * 1024);
  }
}

template <int ROWS>  // 512-thread blocks
__device__ __forceinline__ void stage_swz_8w(u16* lds, const u16* gsrc, int ldk) {
  const int tid = threadIdx.x;
  const int w = tid >> 6, lane = tid & 63;
#pragma unroll
  for (int i = 0; i < ROWS / 64; ++i) {
    const int chunk = i * 8 + w;
    const int row = chunk * 8 + (lane >> 3);
    const int col = ((lane & 7) * 8) ^ ((row & 7) << 3);
    gload16(gsrc + (size_t)row * ldk + col, (char*)lds + chunk * 1024);
  }
}

// ---------------- GroupNorm ----------------
__global__ __launch_bounds__(256) void gn_stats_k(const float* __restrict__ x,
                                                  float* __restrict__ stats) {
  const int bg = blockIdx.x;
  const float4* xp = (const float4*)(x + (size_t)bg * CPG * T);
  float s = 0.f, ss = 0.f;
  for (int i = threadIdx.x; i < CPG * T / 4; i += 256) {
    float4 v = xp[i];
    s += v.x + v.y + v.z + v.w;
    ss += v.x * v.x + v.y * v.y + v.z * v.z + v.w * v.w;
  }
  for (int off = 32; off; off >>= 1) {
    s += __shfl_down(s, off);
    ss += __shfl_down(ss, off);
  }
  __shared__ float red[8];
  const int w = threadIdx.x >> 6;
  if ((threadIdx.x & 63) == 0) { red[w] = s; red[4 + w] = ss; }
  __syncthreads();
  if (threadIdx.x == 0) {
    float S = red[0] + red[1] + red[2] + red[3];
    float SS = red[4] + red[5] + red[6] + red[7];
    const float inv = 1.f / (float)(CPG * T);
    float mean = S * inv;
    float var = SS * inv - mean * mean;
    stats[bg * 2] = mean;
    stats[bg * 2 + 1] = rsqrtf(var + EPS);
  }
}

__global__ __launch_bounds__(256) void gn_apply_k(const float* __restrict__ x,
                                                  const float* __restrict__ stats,
                                                  const float* __restrict__ gsc,
                                                  const float* __restrict__ gbi,
                                                  u16* __restrict__ ht) {
  const int b = blockIdx.y;
  const int t0 = blockIdx.x * 32;
#pragma unroll
  for (int p = 0; p < 2; ++p) {
    const int c = p * 256 + threadIdx.x;
    const int bg = b * G + (c >> 4);
    const float mean = stats[bg * 2], rstd = stats[bg * 2 + 1];
    const float sc = gsc[c] * rstd;
    const float bi = gbi[c] - mean * sc;
    const float4* xp = (const float4*)(x + ((size_t)b * C + c) * T + t0);
#pragma unroll
    for (int j = 0; j < 8; ++j) {
      float4 v = xp[j];
      const int t = t0 + j * 4;
      u16* hp = ht + ((size_t)b * T + t) * C + c;
      hp[0]     = f2bf(v.x * sc + bi);
      hp[C]     = f2bf(v.y * sc + bi);
      hp[2 * C] = f2bf(v.z * sc + bi);
      hp[3 * C] = f2bf(v.w * sc + bi);
    }
  }
}

// ---------------- fp32 -> bf16 weight casts (both weights, one launch) ----------------
__global__ __launch_bounds__(256) void cast_bf_k(const float* __restrict__ s1,
                                                 u16* __restrict__ d1, int n1,
                                                 const float* __restrict__ s2,
                                                 u16* __restrict__ d2, int n2) {
  int i = blockIdx.x * 256 + threadIdx.x;
  const float4* src = (const float4*)s1;
  uint2* dst = (uint2*)d1;
  if (i >= n1) { i -= n1; if (i >= n2) return; src = (const float4*)s2; dst = (uint2*)d2; }
  float4 v = src[i];
  uint2 pk;
  pk.x = (u32)f2bf(v.x) | ((u32)f2bf(v.y) << 16);
  pk.y = (u32)f2bf(v.z) | ((u32)f2bf(v.w) << 16);
  dst[i] = pk;
}

// ---------------- QKV bt-GEMM: C'[t][o] = sum_c h_t[t][c] * W[o][c] ----------------
__global__ __launch_bounds__(256) void qkv_gemm_k(const u16* __restrict__ ht,
                                                  const u16* __restrict__ wq,
                                                  const float* __restrict__ qkvb,
                                                  u16* __restrict__ qo,
                                                  u16* __restrict__ kvo_k,
                                                  u16* __restrict__ kvo_v) {
  __shared__ u16 As[128 * 64];
  __shared__ u16 Bs[128 * 64];
  const int mt = blockIdx.x, nt = blockIdx.y, b = blockIdx.z;
  const u16* Ab = ht + ((size_t)b * T + mt * 128) * C;
  const u16* Bb = wq + (size_t)nt * 128 * C;
  const int tid = threadIdx.x, lane = tid & 63, w = tid >> 6;
  const int wr = w >> 1, wc = w & 1, l15 = lane & 15, lhi = lane >> 4;
  const int swz = (l15 & 7) << 3;

  const f32x4 vzero = {0.f, 0.f, 0.f, 0.f};
  f32x4 acc[4][4];
#pragma unroll
  for (int m = 0; m < 4; ++m)
#pragma unroll
    for (int n = 0; n < 4; ++n) acc[m][n] = vzero;

  for (int kt = 0; kt < C / 64; ++kt) {
    stage_swz_4w<128>(As, Ab + kt * 64, C);
    stage_swz_4w<128>(Bs, Bb + kt * 64, C);
    __syncthreads();
#pragma unroll
    for (int kk = 0; kk < 2; ++kk) {
      const int koff = (kk * 32 + lhi * 8) ^ swz;
      bf16x8 af[4], bfv[4];
#pragma unroll
      for (int m = 0; m < 4; ++m)
        af[m] = *(const bf16x8*)&As[(wr * 64 + m * 16 + l15) * 64 + koff];
#pragma unroll
      for (int n = 0; n < 4; ++n)
        bfv[n] = *(const bf16x8*)&Bs[(wc * 64 + n * 16 + l15) * 64 + koff];
#pragma unroll
      for (int m = 0; m < 4; ++m)
#pragma unroll
        for (int n = 0; n < 4; ++n)
          acc[m][n] = __builtin_amdgcn_mfma_f32_16x16x32_bf16(af[m], bfv[n], acc[m][n], 0, 0, 0);
    }
    __syncthreads();
  }
#pragma unroll
  for (int n = 0; n < 4; ++n) {
    const int o = nt * 128 + wc * 64 + n * 16 + l15;
    const float bias = qkvb[o];
    const int which = o >> 9, rem = o & 511, hh = rem >> 6, d = rem & 63;
    const size_t bh = (size_t)b * H + hh;
#pragma unroll
    for (int m = 0; m < 4; ++m) {
      const int tbase = mt * 128 + wr * 64 + m * 16 + lhi * 4;
#pragma unroll
      for (int r = 0; r < 4; ++r) {
        float val = acc[m][n][r] + bias;
        if (which == 0) val *= SCLQ;   // fold softmax scale into Q
        const u16 bv = f2bf(val);
        const int t = tbase + r;
        if (which == 0)      qo[(bh * T + t) * CH + d] = bv;
        else if (which == 1) kvo_k[(bh * T + t) * CH + d] = bv;
        else                 kvo_v[(bh * CH + d) * T + t] = bv;
      }
    }
  }
}

// ---------------- flash attention: 8 waves = (kv-group, q-set).
// Each q-set owns 32 q-rows; kv-group g handles KV tiles 2p+g. No-max exp2
// softmax is linearly additive -> groups combine via LDS at the end.
// Grid 512 blocks x 8 waves = 4 waves/SIMD (vs 2 before: grid was the cap) --
__global__ __launch_bounds__(512, 4) void attn_k(const u16* __restrict__ q,
                                                 const u16* __restrict__ k,
                                                 const u16* __restrict__ v,
                                                 u16* __restrict__ at) {
  __shared__ u16 Ks[2][128 * 64];     // pair of K tiles (rows 2p*64..2p*64+127)
  __shared__ u16 Vs[2][2][64 * 64];   // pair of V tiles [d][s]
  const int qt = blockIdx.x, bh = blockIdx.y;
  const int tid = threadIdx.x, lane = tid & 63, w = tid >> 6;
  const int qset = w & 3, grp = w >> 2;
  const int l31 = lane & 31, h = lane >> 5;
  const u16* qb = q + (size_t)bh * T * CH;
  const u16* kb = k + (size_t)bh * T * CH;
  const u16* vb = v + (size_t)bh * CH * T;
  constexpr int NP = T / 128;  // 16 tile-pairs

  // Q B-frags straight from global (q-set owns rows qset*32..qset*32+31)
  bf16x8 qf[4];
  {
    const u16* qp = qb + (size_t)(qt * 128 + qset * 32 + l31) * CH + h * 8;
#pragma unroll
    for (int ks = 0; ks < 4; ++ks) qf[ks] = *(const bf16x8*)(qp + ks * 16);
  }

  // prologue: stage pair 0
  stage_swz_8w<128>(Ks[0], kb, CH);
  stage_swz_8w<64>(Vs[0][0], vb, T);
  stage_swz_8w<64>(Vs[0][1], vb + 64, T);
  asm volatile("s_waitcnt vmcnt(0)" ::: "memory");
  __builtin_amdgcn_s_barrier();
  asm volatile("" ::: "memory");

  f32x16 accO0 = {0.f,0.f,0.f,0.f,0.f,0.f,0.f,0.f,0.f,0.f,0.f,0.f,0.f,0.f,0.f,0.f};
  f32x16 accO1 = accO0;
  float lsum = 0.f;
  const int kswz = (l31 & 7) << 3;

  int cur = 0;
  for (int p = 0; p < NP; ++p) {
    // stage next pair first; latency hides under this pair's compute
    if (p + 1 < NP) {
      stage_swz_8w<128>(Ks[cur ^ 1], kb + (size_t)(p + 1) * 128 * CH, CH);
      stage_swz_8w<64>(Vs[cur ^ 1][0], vb + (p + 1) * 128, T);
      stage_swz_8w<64>(Vs[cur ^ 1][1], vb + (p + 1) * 128 + 64, T);
    }
    const u16* Kc = &Ks[cur][grp * 64 * 64];  // this group's K tile
    const u16* Vc = Vs[cur][grp];             // this group's V tile

    // QK^T swapped: accS = S^T[kv][q = l31]
    f32x16 accS0 = {0.f,0.f,0.f,0.f,0.f,0.f,0.f,0.f,0.f,0.f,0.f,0.f,0.f,0.f,0.f,0.f};
    f32x16 accS1 = accS0;
    __builtin_amdgcn_s_setprio(1);
#pragma unroll
    for (int ks = 0; ks < 4; ++ks) {
      const int col = (ks * 16 + h * 8) ^ kswz;
      bf16x8 kf0 = *(const bf16x8*)&Kc[l31 * 64 + col];
      bf16x8 kf1 = *(const bf16x8*)&Kc[(32 + l31) * 64 + col];
      accS0 = __builtin_amdgcn_mfma_f32_32x32x16_bf16(kf0, qf[ks], accS0, 0, 0, 0);
      accS1 = __builtin_amdgcn_mfma_f32_32x32x16_bf16(kf1, qf[ks], accS1, 0, 0, 0);
    }
    __builtin_amdgcn_s_setprio(0);

    // No-max softmax: p = exp2(S); partial lsum; pack to bf16 pairs
    u32 wd0[8], wd1[8];
#pragma unroll
    for (int i = 0; i < 8; ++i) {
      float pa = exp2f(accS0[2 * i]), pb = exp2f(accS0[2 * i + 1]);
      lsum += pa + pb;
      asm("v_cvt_pk_bf16_f32 %0, %1, %2" : "=v"(wd0[i]) : "v"(pa), "v"(pb));
    }
#pragma unroll
    for (int i = 0; i < 8; ++i) {
      float pa = exp2f(accS1[2 * i]), pb = exp2f(accS1[2 * i + 1]);
      lsum += pa + pb;
      asm("v_cvt_pk_bf16_f32 %0, %1, %2" : "=v"(wd1[i]) : "v"(pa), "v"(pb));
    }
    // cross-half exchange in-register (dst.hi<->src.lo)
    pl32swap(wd0[0], wd0[2]); pl32swap(wd0[1], wd0[3]);
    pl32swap(wd0[4], wd0[6]); pl32swap(wd0[5], wd0[7]);
    pl32swap(wd1[0], wd1[2]); pl32swap(wd1[1], wd1[3]);
    pl32swap(wd1[4], wd1[6]); pl32swap(wd1[5], wd1[7]);

    // PV: O[q][d] += P^T[q][s] * V[d][s]
    __builtin_amdgcn_s_setprio(1);
#pragma unroll
    for (int kt = 0; kt < 2; ++kt) {
      const u32* wd = kt ? wd1 : wd0;
      union { u32 u[4]; bf16x8 v8; } fa, fb;
      fa.u[0] = wd[0]; fa.u[1] = wd[1]; fa.u[2] = wd[2]; fa.u[3] = wd[3];
      fb.u[0] = wd[4]; fb.u[1] = wd[5]; fb.u[2] = wd[6]; fb.u[3] = wd[7];
      const int sA = (kt * 32 + h * 8) ^ kswz;
      const int sB = (kt * 32 + 16 + h * 8) ^ kswz;
      {
        bf16x8 vf0 = *(const bf16x8*)&Vc[l31 * 64 + sA];
        bf16x8 vf1 = *(const bf16x8*)&Vc[l31 * 64 + sB];
        accO0 = __builtin_amdgcn_mfma_f32_32x32x16_bf16(fa.v8, vf0, accO0, 0, 0, 0);
        accO0 = __builtin_amdgcn_mfma_f32_32x32x16_bf16(fb.v8, vf1, accO0, 0, 0, 0);
      }
      {
        bf16x8 vf0 = *(const bf16x8*)&Vc[(32 + l31) * 64 + sA];
        bf16x8 vf1 = *(const bf16x8*)&Vc[(32 + l31) * 64 + sB];
        accO1 = __builtin_amdgcn_mfma_f32_32x32x16_bf16(fa.v8, vf0, accO1, 0, 0, 0);
        accO1 = __builtin_amdgcn_mfma_f32_32x32x16_bf16(fb.v8, vf1, accO1, 0, 0, 0);
      }
    }
    __builtin_amdgcn_s_setprio(0);

    asm volatile("s_waitcnt vmcnt(0)" ::: "memory");
    __builtin_amdgcn_s_barrier();
    asm volatile("" ::: "memory");
    cur ^= 1;
  }

  // combine the two kv-groups via LDS (reuse Ks region: 32KB = [128][64] f32)
  lsum += __shfl_xor(lsum, 32);
  float* fO = (float*)&Ks[0][0];
  float* fL = (float*)&Vs[0][0][0];
  if (grp == 1) {
#pragma unroll
    for (int r = 0; r < 16; ++r) {
      const int qrow = (r & 3) + 8 * (r >> 2) + 4 * h;
      float* row = fO + (qset * 32 + qrow) * 64;
      row[l31] = accO0[r];
      row[32 + l31] = accO1[r];
    }
    if (h == 0) fL[qset * 32 + l31] = lsum;
  }
  __builtin_amdgcn_s_barrier();
  if (grp == 0) {
    lsum += fL[qset * 32 + l31];
    const float inv = 1.f / lsum;
    const int bq = bh >> 3, hh = bh & 7;
#pragma unroll
    for (int r = 0; r < 16; ++r) {
      const int qrow = (r & 3) + 8 * (r >> 2) + 4 * h;
      const float invr = __shfl(inv, qrow);  // inv of row-q lives at lane qrow
      const float* row = fO + (qset * 32 + qrow) * 64;
      const float o0 = accO0[r] + row[l31];
      const float o1 = accO1[r] + row[32 + l31];
      const int t = qt * 128 + qset * 32 + qrow;
      u16* op = at + ((size_t)bq * T + t) * C + hh * 64 + l31;
      op[0]  = f2bf(o0 * invr);
      op[32] = f2bf(o1 * invr);
    }
  }
}

// ---------------- proj bt-GEMM + bias + residual ----------------
__global__ __launch_bounds__(256) void proj_gemm_k(const u16* __restrict__ at,
                                                   const u16* __restrict__ wp,
                                                   const float* __restrict__ pb,
                                                   const float* __restrict__ x,
                                                   float* __restrict__ out) {
  __shared__ u16 As[128 * 64];
  __shared__ u16 Bs[128 * 64];
  const int mt = blockIdx.x, nt = blockIdx.y, b = blockIdx.z;
  const u16* Ab = at + ((size_t)b * T + mt * 128) * C;
  const u16* Bb = wp + (size_t)nt * 128 * C;
  const int tid = threadIdx.x, lane = tid & 63, w = tid >> 6;
  const int wr = w >> 1, wc = w & 1, l15 = lane & 15, lhi = lane >> 4;
  const int swz = (l15 & 7) << 3;

  const f32x4 vzero = {0.f, 0.f, 0.f, 0.f};
  f32x4 acc[4][4];
#pragma unroll
  for (int m = 0; m < 4; ++m)
#pragma unroll
    for (int n = 0; n < 4; ++n) acc[m][n] = vzero;

  for (int kt = 0; kt < C / 64; ++kt) {
    stage_swz_4w<128>(As, Ab + kt * 64, C);
    stage_swz_4w<128>(Bs, Bb + kt * 64, C);
    __syncthreads();
#pragma unroll
    for (int kk = 0; kk < 2; ++kk) {
      const int koff = (kk * 32 + lhi * 8) ^ swz;
      bf16x8 af[4], bfv[4];
#pragma unroll
      for (int m = 0; m < 4; ++m)
        af[m] = *(const bf16x8*)&As[(wr * 64 + m * 16 + l15) * 64 + koff];
#pragma unroll
      for (int n = 0; n < 4; ++n)
        bfv[n] = *(const bf16x8*)&Bs[(wc * 64 + n * 16 + l15) * 64 + koff];
#pragma unroll
      for (int m = 0; m < 4; ++m)
#pragma unroll
        for (int n = 0; n < 4; ++n)
          acc[m][n] = __builtin_amdgcn_mfma_f32_16x16x32_bf16(af[m], bfv[n], acc[m][n], 0, 0, 0);
    }
    __syncthreads();
  }
#pragma unroll
  for (int n = 0; n < 4; ++n) {
    const int o = nt * 128 + wc * 64 + n * 16 + l15;
    const float bias = pb[o];
#pragma unroll
    for (int m = 0; m < 4; ++m) {
      const int tbase = mt * 128 + wr * 64 + m * 16 + lhi * 4;
#pragma unroll
      for (int r = 0; r < 4; ++r) {
        const int t = tbase + r;
        const size_t idx = ((size_t)b * C + o) * T + t;
        out[idx] = x[idx] + acc[m][n][r] + bias;
      }
    }
  }
}

extern "C" void kernel_launch(void* const* d_in, const int* in_sizes, int n_in,
                              void* d_out, int out_size, void* d_ws, size_t ws_size,
                              hipStream_t stream) {
  const float* x     = (const float*)d_in[0];
  const float* gsc   = (const float*)d_in[1];
  const float* gbi   = (const float*)d_in[2];
  const float* qkvw  = (const float*)d_in[3];
  const float* qkvb  = (const float*)d_in[4];
  const float* projw = (const float*)d_in[5];
  const float* projb = (const float*)d_in[6];
  float* out = (float*)d_out;

  char* ws = (char*)d_ws;
  float* stats = (float*)ws;
  u16* wq = (u16*)(ws + 1024);
  u16* wp = (u16*)(ws + 1024 + 1572864);
  u16* ht = (u16*)(ws + 2098176);
  u16* qo = (u16*)(ws + 10486784);
  u16* ko = (u16*)(ws + 18875392);
  u16* vo = (u16*)(ws + 27264000);
  u16* at = ht;  // reuse: ht dead after qkv_gemm

  cast_bf_k<<<1024, 256, 0, stream>>>(qkvw, wq, 196608, projw, wp, 65536);
  gn_stats_k<<<B * G, 256, 0, stream>>>(x, stats);
  gn_apply_k<<<dim3(T / 32, B), 256, 0, stream>>>(x, stats, gsc, gbi, ht);
  qkv_gemm_k<<<dim3(T / 128, (3 * C) / 128, B), 256, 0, stream>>>(ht, wq, qkvb, qo, ko, vo);
  attn_k<<<dim3(T / 128, B * H), 512, 0, stream>>>(qo, ko, vo, at);
  proj_gemm_k<<<dim3(T / 128, C / 128, B), 256, 0, stream>>>(at, wp, projb, x, out);
}

// Round 8
// 120.395 us; speedup vs baseline: 2.0068x; 1.1609x over previous
//
#include <hip/hip_runtime.h>

typedef short bf16x8 __attribute__((ext_vector_type(8)));
typedef float f32x4 __attribute__((ext_vector_type(4)));
typedef float f32x16 __attribute__((ext_vector_type(16)));
typedef unsigned short u16;
typedef unsigned int u32;

constexpr int B = 4, C = 512, T = 2048, H = 8, G = 32;
constexpr int CH = C / H;   // 64
constexpr int CPG = C / G;  // 16
constexpr float EPS = 1e-5f;
// softmax scale folded into Q: p = exp2(S_raw * 0.125 * log2(e))
constexpr float SCLQ = 0.18033688011112042f;

__device__ __forceinline__ u16 f2bf(float f) {
  union { float f; u32 u; } v; v.f = f;
  return (u16)((v.u + 0x7FFFu + ((v.u >> 16) & 1u)) >> 16);
}

__device__ __forceinline__ void gload16(const void* g, void* lds) {
  __builtin_amdgcn_global_load_lds(
      (const __attribute__((address_space(1))) void*)g,
      (__attribute__((address_space(3))) void*)lds, 16, 0, 0);
}

// v_permlane32_swap_b32: a.hi <-> b.lo (cross-half exchange for the PV
// A-fragment; VALU pipe, replaces ds_bpermute + cndmask)
__device__ __forceinline__ void pl32swap(u32& a, u32& b) {
  asm("v_permlane32_swap_b32 %0, %1" : "+v"(a), "+v"(b));
}

// XOR-swizzled staging: ROWS x 64 bf16 tile -> linear LDS [ROWS][64].
// Global source column pre-swizzled; reads apply col ^ ((row&7)<<3).
template <int ROWS>  // 256-thread blocks
__device__ __forceinline__ void stage_swz_4w(u16* lds, const u16* gsrc, int ldk) {
  const int tid = threadIdx.x;
  const int w = tid >> 6, lane = tid & 63;
#pragma unroll
  for (int i = 0; i < ROWS / 32; ++i) {
    const int chunk = i * 4 + w;                 // 1KB chunk = 8 rows of 128B
    const int row = chunk * 8 + (lane >> 3);
    const int col = ((lane & 7) * 8) ^ ((row & 7) << 3);
    gload16(gsrc + (size_t)row * ldk + col, (char*)lds + chunk * 1024);
  }
}

template <int ROWS>  // 512-thread blocks
__device__ __forceinline__ void stage_swz_8w(u16* lds, const u16* gsrc, int ldk) {
  const int tid = threadIdx.x;
  const int w = tid >> 6, lane = tid & 63;
#pragma unroll
  for (int i = 0; i < ROWS / 64; ++i) {
    const int chunk = i * 8 + w;
    const int row = chunk * 8 + (lane >> 3);
    const int col = ((lane & 7) * 8) ^ ((row & 7) << 3);
    gload16(gsrc + (size_t)row * ldk + col, (char*)lds + chunk * 1024);
  }
}

// ---------------- prep: weight casts + GroupNorm stats (one launch) ----------------
__global__ __launch_bounds__(256) void prep_k(const float* __restrict__ x,
                                              float* __restrict__ stats,
                                              const float* __restrict__ s1,
                                              u16* __restrict__ d1, int n1,
                                              const float* __restrict__ s2,
                                              u16* __restrict__ d2, int n2) {
  __shared__ float red[8];
  const int bid = blockIdx.x;
  if (bid < 1024) {  // ---- weight cast path ----
    int i = bid * 256 + threadIdx.x;
    const float4* src = (const float4*)s1;
    uint2* dst = (uint2*)d1;
    if (i >= n1) { i -= n1; if (i >= n2) return; src = (const float4*)s2; dst = (uint2*)d2; }
    float4 v = src[i];
    uint2 pk;
    pk.x = (u32)f2bf(v.x) | ((u32)f2bf(v.y) << 16);
    pk.y = (u32)f2bf(v.z) | ((u32)f2bf(v.w) << 16);
    dst[i] = pk;
    return;
  }
  // ---- gn_stats path ----
  const int bg = bid - 1024;
  const float4* xp = (const float4*)(x + (size_t)bg * CPG * T);
  float s = 0.f, ss = 0.f;
  for (int i = threadIdx.x; i < CPG * T / 4; i += 256) {
    float4 v = xp[i];
    s += v.x + v.y + v.z + v.w;
    ss += v.x * v.x + v.y * v.y + v.z * v.z + v.w * v.w;
  }
  for (int off = 32; off; off >>= 1) {
    s += __shfl_down(s, off);
    ss += __shfl_down(ss, off);
  }
  const int w = threadIdx.x >> 6;
  if ((threadIdx.x & 63) == 0) { red[w] = s; red[4 + w] = ss; }
  __syncthreads();
  if (threadIdx.x == 0) {
    float S = red[0] + red[1] + red[2] + red[3];
    float SS = red[4] + red[5] + red[6] + red[7];
    const float inv = 1.f / (float)(CPG * T);
    float mean = S * inv;
    float var = SS * inv - mean * mean;
    stats[bg * 2] = mean;
    stats[bg * 2 + 1] = rsqrtf(var + EPS);
  }
}

__global__ __launch_bounds__(256) void gn_apply_k(const float* __restrict__ x,
                                                  const float* __restrict__ stats,
                                                  const float* __restrict__ gsc,
                                                  const float* __restrict__ gbi,
                                                  u16* __restrict__ ht) {
  const int b = blockIdx.y;
  const int t0 = blockIdx.x * 32;
#pragma unroll
  for (int p = 0; p < 2; ++p) {
    const int c = p * 256 + threadIdx.x;
    const int bg = b * G + (c >> 4);
    const float mean = stats[bg * 2], rstd = stats[bg * 2 + 1];
    const float sc = gsc[c] * rstd;
    const float bi = gbi[c] - mean * sc;
    const float4* xp = (const float4*)(x + ((size_t)b * C + c) * T + t0);
#pragma unroll
    for (int j = 0; j < 8; ++j) {
      float4 v = xp[j];
      const int t = t0 + j * 4;
      u16* hp = ht + ((size_t)b * T + t) * C + c;
      hp[0]     = f2bf(v.x * sc + bi);
      hp[C]     = f2bf(v.y * sc + bi);
      hp[2 * C] = f2bf(v.z * sc + bi);
      hp[3 * C] = f2bf(v.w * sc + bi);
    }
  }
}

// ---------------- QKV bt-GEMM: C'[t][o] = sum_c h_t[t][c] * W[o][c] ----------------
// 1D grid, XCD-chunked: each XCD gets 8 consecutive mt (same b) x all 12 nt
// -> 1MB A-panel + per-K-step B tiles stay in that XCD's L2.
__global__ __launch_bounds__(256) void qkv_gemm_k(const u16* __restrict__ ht,
                                                  const u16* __restrict__ wq,
                                                  const float* __restrict__ qkvb,
                                                  u16* __restrict__ qo,
                                                  u16* __restrict__ kvo_k,
                                                  u16* __restrict__ kvo_v) {
  __shared__ u16 As[128 * 64];
  __shared__ u16 Bs[128 * 64];
  const int bid = blockIdx.x;
  const int wg = (bid & 7) * 96 + (bid >> 3);   // 768 = 8 x 96, bijective
  const int nt = wg % 12;
  const int mtb = wg / 12;
  const int mt = mtb & 15, b = mtb >> 4;
  const u16* Ab = ht + ((size_t)b * T + mt * 128) * C;
  const u16* Bb = wq + (size_t)nt * 128 * C;
  const int tid = threadIdx.x, lane = tid & 63, w = tid >> 6;
  const int wr = w >> 1, wc = w & 1, l15 = lane & 15, lhi = lane >> 4;
  const int swz = (l15 & 7) << 3;

  const f32x4 vzero = {0.f, 0.f, 0.f, 0.f};
  f32x4 acc[4][4];
#pragma unroll
  for (int m = 0; m < 4; ++m)
#pragma unroll
    for (int n = 0; n < 4; ++n) acc[m][n] = vzero;

  for (int kt = 0; kt < C / 64; ++kt) {
    stage_swz_4w<128>(As, Ab + kt * 64, C);
    stage_swz_4w<128>(Bs, Bb + kt * 64, C);
    __syncthreads();
#pragma unroll
    for (int kk = 0; kk < 2; ++kk) {
      const int koff = (kk * 32 + lhi * 8) ^ swz;
      bf16x8 af[4], bfv[4];
#pragma unroll
      for (int m = 0; m < 4; ++m)
        af[m] = *(const bf16x8*)&As[(wr * 64 + m * 16 + l15) * 64 + koff];
#pragma unroll
      for (int n = 0; n < 4; ++n)
        bfv[n] = *(const bf16x8*)&Bs[(wc * 64 + n * 16 + l15) * 64 + koff];
#pragma unroll
      for (int m = 0; m < 4; ++m)
#pragma unroll
        for (int n = 0; n < 4; ++n)
          acc[m][n] = __builtin_amdgcn_mfma_f32_16x16x32_bf16(af[m], bfv[n], acc[m][n], 0, 0, 0);
    }
    __syncthreads();
  }
#pragma unroll
  for (int n = 0; n < 4; ++n) {
    const int o = nt * 128 + wc * 64 + n * 16 + l15;
    const float bias = qkvb[o];
    const int which = o >> 9, rem = o & 511, hh = rem >> 6, d = rem & 63;
    const size_t bh = (size_t)b * H + hh;
#pragma unroll
    for (int m = 0; m < 4; ++m) {
      const int tbase = mt * 128 + wr * 64 + m * 16 + lhi * 4;
#pragma unroll
      for (int r = 0; r < 4; ++r) {
        float val = acc[m][n][r] + bias;
        if (which == 0) val *= SCLQ;   // fold softmax scale into Q
        const u16 bv = f2bf(val);
        const int t = tbase + r;
        if (which == 0)      qo[(bh * T + t) * CH + d] = bv;
        else if (which == 1) kvo_k[(bh * T + t) * CH + d] = bv;
        else                 kvo_v[(bh * CH + d) * T + t] = bv;
      }
    }
  }
}

// ---------------- flash attention: 8 waves = (kv-group, q-set), 32x32x16 MFMA,
// swapped QK^T, in-register no-max softmax, lsum via ones-column MFMA.
// XCD-swizzled: each XCD owns 4 bh -> K/V L2-resident. ----------------------
__global__ __launch_bounds__(512, 4) void attn_k(const u16* __restrict__ q,
                                                 const u16* __restrict__ k,
                                                 const u16* __restrict__ v,
                                                 u16* __restrict__ at) {
  __shared__ u16 Ks[2][128 * 64];     // pair of K tiles
  __shared__ u16 Vs[2][2][64 * 64];   // pair of V tiles [d][s]
  const int lin = blockIdx.x + (blockIdx.y << 4);
  const int wg = (lin & 7) * 64 + (lin >> 3);   // 512 = 8 x 64, bijective
  const int qt = wg & 15, bh = wg >> 4;
  const int tid = threadIdx.x, lane = tid & 63, w = tid >> 6;
  const int qset = w & 3, grp = w >> 2;
  const int l31 = lane & 31, h = lane >> 5;
  const u16* qb = q + (size_t)bh * T * CH;
  const u16* kb = k + (size_t)bh * T * CH;
  const u16* vb = v + (size_t)bh * CH * T;
  constexpr int NP = T / 128;  // 16 tile-pairs

  // Q B-frags straight from global (q-set owns rows qset*32..qset*32+31)
  bf16x8 qf[4];
  {
    const u16* qp = qb + (size_t)(qt * 128 + qset * 32 + l31) * CH + h * 8;
#pragma unroll
    for (int ks = 0; ks < 4; ++ks) qf[ks] = *(const bf16x8*)(qp + ks * 16);
  }
  // ones B-frag for the lsum MFMA (bf16 1.0 = 0x3F80)
  union { u32 u[4]; bf16x8 v8; } ones;
#pragma unroll
  for (int i = 0; i < 4; ++i) ones.u[i] = 0x3F803F80u;

  // prologue: stage pair 0
  stage_swz_8w<128>(Ks[0], kb, CH);
  stage_swz_8w<64>(Vs[0][0], vb, T);
  stage_swz_8w<64>(Vs[0][1], vb + 64, T);
  asm volatile("s_waitcnt vmcnt(0)" ::: "memory");
  __builtin_amdgcn_s_barrier();
  asm volatile("" ::: "memory");

  f32x16 accO0 = {0.f,0.f,0.f,0.f,0.f,0.f,0.f,0.f,0.f,0.f,0.f,0.f,0.f,0.f,0.f,0.f};
  f32x16 accO1 = accO0;
  f32x16 accL = accO0;   // lsum accumulator: accL[r] = sum_kv P[kv][qrow(r)]
  const int kswz = (l31 & 7) << 3;

  int cur = 0;
  for (int p = 0; p < NP; ++p) {
    // stage next pair first; latency (L2-hit post-swizzle) hides under compute
    if (p + 1 < NP) {
      stage_swz_8w<128>(Ks[cur ^ 1], kb + (size_t)(p + 1) * 128 * CH, CH);
      stage_swz_8w<64>(Vs[cur ^ 1][0], vb + (p + 1) * 128, T);
      stage_swz_8w<64>(Vs[cur ^ 1][1], vb + (p + 1) * 128 + 64, T);
    }
    const u16* Kc = &Ks[cur][grp * 64 * 64];  // this group's K tile
    const u16* Vc = Vs[cur][grp];             // this group's V tile

    // QK^T swapped: accS = S^T[kv][q = l31]
    f32x16 accS0 = {0.f,0.f,0.f,0.f,0.f,0.f,0.f,0.f,0.f,0.f,0.f,0.f,0.f,0.f,0.f,0.f};
    f32x16 accS1 = accS0;
    __builtin_amdgcn_s_setprio(1);
#pragma unroll
    for (int ks = 0; ks < 4; ++ks) {
      const int col = (ks * 16 + h * 8) ^ kswz;
      bf16x8 kf0 = *(const bf16x8*)&Kc[l31 * 64 + col];
      bf16x8 kf1 = *(const bf16x8*)&Kc[(32 + l31) * 64 + col];
      accS0 = __builtin_amdgcn_mfma_f32_32x32x16_bf16(kf0, qf[ks], accS0, 0, 0, 0);
      accS1 = __builtin_amdgcn_mfma_f32_32x32x16_bf16(kf1, qf[ks], accS1, 0, 0, 0);
    }
    __builtin_amdgcn_s_setprio(0);

    // No-max softmax: p = exp2(S) (scale pre-folded into Q); raw v_exp_f32
    // (inputs bounded, no range fixup needed); pack to bf16 pairs
    u32 wd0[8], wd1[8];
#pragma unroll
    for (int i = 0; i < 8; ++i) {
      float pa = __builtin_amdgcn_exp2f(accS0[2 * i]);
      float pb = __builtin_amdgcn_exp2f(accS0[2 * i + 1]);
      asm("v_cvt_pk_bf16_f32 %0, %1, %2" : "=v"(wd0[i]) : "v"(pa), "v"(pb));
    }
#pragma unroll
    for (int i = 0; i < 8; ++i) {
      float pa = __builtin_amdgcn_exp2f(accS1[2 * i]);
      float pb = __builtin_amdgcn_exp2f(accS1[2 * i + 1]);
      asm("v_cvt_pk_bf16_f32 %0, %1, %2" : "=v"(wd1[i]) : "v"(pa), "v"(pb));
    }
    // cross-half exchange in-register (dst.hi<->src.lo)
    pl32swap(wd0[0], wd0[2]); pl32swap(wd0[1], wd0[3]);
    pl32swap(wd0[4], wd0[6]); pl32swap(wd0[5], wd0[7]);
    pl32swap(wd1[0], wd1[2]); pl32swap(wd1[1], wd1[3]);
    pl32swap(wd1[4], wd1[6]); pl32swap(wd1[5], wd1[7]);

    // PV: O[q][d] += P^T[q][s] * V[d][s]; lsum via ones-column MFMA
    __builtin_amdgcn_s_setprio(1);
#pragma unroll
    for (int kt = 0; kt < 2; ++kt) {
      const u32* wd = kt ? wd1 : wd0;
      union { u32 u[4]; bf16x8 v8; } fa, fb;
      fa.u[0] = wd[0]; fa.u[1] = wd[1]; fa.u[2] = wd[2]; fa.u[3] = wd[3];
      fb.u[0] = wd[4]; fb.u[1] = wd[5]; fb.u[2] = wd[6]; fb.u[3] = wd[7];
      const int sA = (kt * 32 + h * 8) ^ kswz;
      const int sB = (kt * 32 + 16 + h * 8) ^ kswz;
      {
        bf16x8 vf0 = *(const bf16x8*)&Vc[l31 * 64 + sA];
        bf16x8 vf1 = *(const bf16x8*)&Vc[l31 * 64 + sB];
        accO0 = __builtin_amdgcn_mfma_f32_32x32x16_bf16(fa.v8, vf0, accO0, 0, 0, 0);
        accO0 = __builtin_amdgcn_mfma_f32_32x32x16_bf16(fb.v8, vf1, accO0, 0, 0, 0);
      }
      {
        bf16x8 vf0 = *(const bf16x8*)&Vc[(32 + l31) * 64 + sA];
        bf16x8 vf1 = *(const bf16x8*)&Vc[(32 + l31) * 64 + sB];
        accO1 = __builtin_amdgcn_mfma_f32_32x32x16_bf16(fa.v8, vf0, accO1, 0, 0, 0);
        accO1 = __builtin_amdgcn_mfma_f32_32x32x16_bf16(fb.v8, vf1, accO1, 0, 0, 0);
      }
      accL = __builtin_amdgcn_mfma_f32_32x32x16_bf16(fa.v8, ones.v8, accL, 0, 0, 0);
      accL = __builtin_amdgcn_mfma_f32_32x32x16_bf16(fb.v8, ones.v8, accL, 0, 0, 0);
    }
    __builtin_amdgcn_s_setprio(0);

    asm volatile("s_waitcnt vmcnt(0)" ::: "memory");
    __builtin_amdgcn_s_barrier();
    asm volatile("" ::: "memory");
    cur ^= 1;
  }

  // combine the two kv-groups via LDS (reuse Ks: 32KB = [128][64] f32)
  float* fO = (float*)&Ks[0][0];
  float* fL = (float*)&Vs[0][0][0];
  if (grp == 1) {
#pragma unroll
    for (int r = 0; r < 16; ++r) {
      const int qrow = (r & 3) + 8 * (r >> 2) + 4 * h;
      float* row = fO + (qset * 32 + qrow) * 64;
      row[l31] = accO0[r];
      row[32 + l31] = accO1[r];
      if (l31 == 0) fL[qset * 32 + qrow] = accL[r];
    }
  }
  __syncthreads();
  if (grp == 0) {
    const int bq = bh >> 3, hh = bh & 7;
#pragma unroll
    for (int r = 0; r < 16; ++r) {
      const int qrow = (r & 3) + 8 * (r >> 2) + 4 * h;
      const float denom = accL[r] + fL[qset * 32 + qrow];
      const float invr = __builtin_amdgcn_rcpf(denom);
      const float* row = fO + (qset * 32 + qrow) * 64;
      const float o0 = accO0[r] + row[l31];
      const float o1 = accO1[r] + row[32 + l31];
      const int t = qt * 128 + qset * 32 + qrow;
      u16* op = at + ((size_t)bq * T + t) * C + hh * 64 + l31;
      op[0]  = f2bf(o0 * invr);
      op[32] = f2bf(o1 * invr);
    }
  }
}

// ---------------- proj bt-GEMM + bias + residual (XCD-chunked 1D grid) ------
__global__ __launch_bounds__(256) void proj_gemm_k(const u16* __restrict__ at,
                                                   const u16* __restrict__ wp,
                                                   const float* __restrict__ pb,
                                                   const float* __restrict__ x,
                                                   float* __restrict__ out) {
  __shared__ u16 As[128 * 64];
  __shared__ u16 Bs[128 * 64];
  const int bid = blockIdx.x;
  const int wg = (bid & 7) * 32 + (bid >> 3);   // 256 = 8 x 32, bijective
  const int nt = wg & 3;
  const int mtb = wg >> 2;
  const int mt = mtb & 15, b = mtb >> 4;
  const u16* Ab = at + ((size_t)b * T + mt * 128) * C;
  const u16* Bb = wp + (size_t)nt * 128 * C;
  const int tid = threadIdx.x, lane = tid & 63, w = tid >> 6;
  const int wr = w >> 1, wc = w & 1, l15 = lane & 15, lhi = lane >> 4;
  const int swz = (l15 & 7) << 3;

  const f32x4 vzero = {0.f, 0.f, 0.f, 0.f};
  f32x4 acc[4][4];
#pragma unroll
  for (int m = 0; m < 4; ++m)
#pragma unroll
    for (int n = 0; n < 4; ++n) acc[m][n] = vzero;

  for (int kt = 0; kt < C / 64; ++kt) {
    stage_swz_4w<128>(As, Ab + kt * 64, C);
    stage_swz_4w<128>(Bs, Bb + kt * 64, C);
    __syncthreads();
#pragma unroll
    for (int kk = 0; kk < 2; ++kk) {
      const int koff = (kk * 32 + lhi * 8) ^ swz;
      bf16x8 af[4], bfv[4];
#pragma unroll
      for (int m = 0; m < 4; ++m)
        af[m] = *(const bf16x8*)&As[(wr * 64 + m * 16 + l15) * 64 + koff];
#pragma unroll
      for (int n = 0; n < 4; ++n)
        bfv[n] = *(const bf16x8*)&Bs[(wc * 64 + n * 16 + l15) * 64 + koff];
#pragma unroll
      for (int m = 0; m < 4; ++m)
#pragma unroll
        for (int n = 0; n < 4; ++n)
          acc[m][n] = __builtin_amdgcn_mfma_f32_16x16x32_bf16(af[m], bfv[n], acc[m][n], 0, 0, 0);
    }
    __syncthreads();
  }
#pragma unroll
  for (int n = 0; n < 4; ++n) {
    const int o = nt * 128 + wc * 64 + n * 16 + l15;
    const float bias = pb[o];
#pragma unroll
    for (int m = 0; m < 4; ++m) {
      const int tbase = mt * 128 + wr * 64 + m * 16 + lhi * 4;
#pragma unroll
      for (int r = 0; r < 4; ++r) {
        const int t = tbase + r;
        const size_t idx = ((size_t)b * C + o) * T + t;
        out[idx] = x[idx] + acc[m][n][r] + bias;
      }
    }
  }
}

extern "C" void kernel_launch(void* const* d_in, const int* in_sizes, int n_in,
                              void* d_out, int out_size, void* d_ws, size_t ws_size,
                              hipStream_t stream) {
  const float* x     = (const float*)d_in[0];
  const float* gsc   = (const float*)d_in[1];
  const float* gbi   = (const float*)d_in[2];
  const float* qkvw  = (const float*)d_in[3];
  const float* qkvb  = (const float*)d_in[4];
  const float* projw = (const float*)d_in[5];
  const float* projb = (const float*)d_in[6];
  float* out = (float*)d_out;

  char* ws = (char*)d_ws;
  float* stats = (float*)ws;
  u16* wq = (u16*)(ws + 1024);
  u16* wp = (u16*)(ws + 1024 + 1572864);
  u16* ht = (u16*)(ws + 2098176);
  u16* qo = (u16*)(ws + 10486784);
  u16* ko = (u16*)(ws + 18875392);
  u16* vo = (u16*)(ws + 27264000);
  u16* at = ht;  // reuse: ht dead after qkv_gemm

  prep_k<<<1152, 256, 0, stream>>>(x, stats, qkvw, wq, 196608, projw, wp, 65536);
  gn_apply_k<<<dim3(T / 32, B), 256, 0, stream>>>(x, stats, gsc, gbi, ht);
  qkv_gemm_k<<<768, 256, 0, stream>>>(ht, wq, qkvb, qo, ko, vo);
  attn_k<<<dim3(T / 128, B * H), 512, 0, stream>>>(qo, ko, vo, at);
  proj_gemm_k<<<256, 256, 0, stream>>>(at, wp, projb, x, out);
}

// Round 9
// 114.063 us; speedup vs baseline: 2.1182x; 1.0555x over previous
//
#include <hip/hip_runtime.h>

typedef short bf16x8 __attribute__((ext_vector_type(8)));
typedef float f32x4 __attribute__((ext_vector_type(4)));
typedef float f32x16 __attribute__((ext_vector_type(16)));
typedef unsigned short u16;
typedef unsigned int u32;

constexpr int B = 4, C = 512, T = 2048, H = 8, G = 32;
constexpr int CH = C / H;   // 64
constexpr int CPG = C / G;  // 16
constexpr float EPS = 1e-5f;
// softmax scale folded into Q: p = exp2(S_raw * 0.125 * log2(e))
constexpr float SCLQ = 0.18033688011112042f;

__device__ __forceinline__ u16 f2bf(float f) {
  union { float f; u32 u; } v; v.f = f;
  return (u16)((v.u + 0x7FFFu + ((v.u >> 16) & 1u)) >> 16);
}

__device__ __forceinline__ void gload16(const void* g, void* lds) {
  __builtin_amdgcn_global_load_lds(
      (const __attribute__((address_space(1))) void*)g,
      (__attribute__((address_space(3))) void*)lds, 16, 0, 0);
}

// v_permlane32_swap_b32: a.hi <-> b.lo (cross-half exchange for the PV
// A-fragment; VALU pipe, replaces ds_bpermute + cndmask)
__device__ __forceinline__ void pl32swap(u32& a, u32& b) {
  asm("v_permlane32_swap_b32 %0, %1" : "+v"(a), "+v"(b));
}

// XOR-swizzled staging: ROWS x 64 bf16 tile -> linear LDS [ROWS][64].
// Global source column pre-swizzled; reads apply col ^ ((row&7)<<3).
template <int ROWS>  // 256-thread blocks
__device__ __forceinline__ void stage_swz_4w(u16* lds, const u16* gsrc, int ldk) {
  const int tid = threadIdx.x;
  const int w = tid >> 6, lane = tid & 63;
#pragma unroll
  for (int i = 0; i < ROWS / 32; ++i) {
    const int chunk = i * 4 + w;                 // 1KB chunk = 8 rows of 128B
    const int row = chunk * 8 + (lane >> 3);
    const int col = ((lane & 7) * 8) ^ ((row & 7) << 3);
    gload16(gsrc + (size_t)row * ldk + col, (char*)lds + chunk * 1024);
  }
}

template <int ROWS>  // 512-thread blocks
__device__ __forceinline__ void stage_swz_8w(u16* lds, const u16* gsrc, int ldk) {
  const int tid = threadIdx.x;
  const int w = tid >> 6, lane = tid & 63;
#pragma unroll
  for (int i = 0; i < ROWS / 64; ++i) {
    const int chunk = i * 8 + w;
    const int row = chunk * 8 + (lane >> 3);
    const int col = ((lane & 7) * 8) ^ ((row & 7) << 3);
    gload16(gsrc + (size_t)row * ldk + col, (char*)lds + chunk * 1024);
  }
}

// ---------------- prep: weight casts + GroupNorm stats (one launch) ----------------
__global__ __launch_bounds__(256) void prep_k(const float* __restrict__ x,
                                              float* __restrict__ stats,
                                              const float* __restrict__ s1,
                                              u16* __restrict__ d1, int n1,
                                              const float* __restrict__ s2,
                                              u16* __restrict__ d2, int n2) {
  __shared__ float red[8];
  const int bid = blockIdx.x;
  if (bid < 1024) {  // ---- weight cast path ----
    int i = bid * 256 + threadIdx.x;
    const float4* src = (const float4*)s1;
    uint2* dst = (uint2*)d1;
    if (i >= n1) { i -= n1; if (i >= n2) return; src = (const float4*)s2; dst = (uint2*)d2; }
    float4 v = src[i];
    uint2 pk;
    pk.x = (u32)f2bf(v.x) | ((u32)f2bf(v.y) << 16);
    pk.y = (u32)f2bf(v.z) | ((u32)f2bf(v.w) << 16);
    dst[i] = pk;
    return;
  }
  // ---- gn_stats path ----
  const int bg = bid - 1024;
  const float4* xp = (const float4*)(x + (size_t)bg * CPG * T);
  float s = 0.f, ss = 0.f;
  for (int i = threadIdx.x; i < CPG * T / 4; i += 256) {
    float4 v = xp[i];
    s += v.x + v.y + v.z + v.w;
    ss += v.x * v.x + v.y * v.y + v.z * v.z + v.w * v.w;
  }
  for (int off = 32; off; off >>= 1) {
    s += __shfl_down(s, off);
    ss += __shfl_down(ss, off);
  }
  const int w = threadIdx.x >> 6;
  if ((threadIdx.x & 63) == 0) { red[w] = s; red[4 + w] = ss; }
  __syncthreads();
  if (threadIdx.x == 0) {
    float S = red[0] + red[1] + red[2] + red[3];
    float SS = red[4] + red[5] + red[6] + red[7];
    const float inv = 1.f / (float)(CPG * T);
    float mean = S * inv;
    float var = SS * inv - mean * mean;
    stats[bg * 2] = mean;
    stats[bg * 2 + 1] = rsqrtf(var + EPS);
  }
}

__global__ __launch_bounds__(256) void gn_apply_k(const float* __restrict__ x,
                                                  const float* __restrict__ stats,
                                                  const float* __restrict__ gsc,
                                                  const float* __restrict__ gbi,
                                                  u16* __restrict__ ht) {
  const int b = blockIdx.y;
  const int t0 = blockIdx.x * 32;
#pragma unroll
  for (int p = 0; p < 2; ++p) {
    const int c = p * 256 + threadIdx.x;
    const int bg = b * G + (c >> 4);
    const float mean = stats[bg * 2], rstd = stats[bg * 2 + 1];
    const float sc = gsc[c] * rstd;
    const float bi = gbi[c] - mean * sc;
    const float4* xp = (const float4*)(x + ((size_t)b * C + c) * T + t0);
#pragma unroll
    for (int j = 0; j < 8; ++j) {
      float4 v = xp[j];
      const int t = t0 + j * 4;
      u16* hp = ht + ((size_t)b * T + t) * C + c;
      hp[0]     = f2bf(v.x * sc + bi);
      hp[C]     = f2bf(v.y * sc + bi);
      hp[2 * C] = f2bf(v.z * sc + bi);
      hp[3 * C] = f2bf(v.w * sc + bi);
    }
  }
}

// ---------------- QKV bt-GEMM: C'[t][o] = sum_c h_t[t][c] * W[o][c] ----------------
// 512 threads / 8 waves (wave tile 32x64): 768 blocks x 8 = 24 waves/CU for
// latency hiding. XCD-chunked 1D grid (L2-resident A-panel + B tiles).
__global__ __launch_bounds__(512, 2) void qkv_gemm_k(const u16* __restrict__ ht,
                                                     const u16* __restrict__ wq,
                                                     const float* __restrict__ qkvb,
                                                     u16* __restrict__ qo,
                                                     u16* __restrict__ kvo_k,
                                                     u16* __restrict__ kvo_v) {
  __shared__ u16 As[128 * 64];
  __shared__ u16 Bs[128 * 64];
  const int bid = blockIdx.x;
  const int wg = (bid & 7) * 96 + (bid >> 3);   // 768 = 8 x 96, bijective
  const int nt = wg % 12;
  const int mtb = wg / 12;
  const int mt = mtb & 15, b = mtb >> 4;
  const u16* Ab = ht + ((size_t)b * T + mt * 128) * C;
  const u16* Bb = wq + (size_t)nt * 128 * C;
  const int tid = threadIdx.x, lane = tid & 63, w = tid >> 6;
  const int wr = w >> 1, wc = w & 1, l15 = lane & 15, lhi = lane >> 4;
  const int swz = (l15 & 7) << 3;

  const f32x4 vzero = {0.f, 0.f, 0.f, 0.f};
  f32x4 acc[2][4];
#pragma unroll
  for (int m = 0; m < 2; ++m)
#pragma unroll
    for (int n = 0; n < 4; ++n) acc[m][n] = vzero;

  for (int kt = 0; kt < C / 64; ++kt) {
    stage_swz_8w<128>(As, Ab + kt * 64, C);
    stage_swz_8w<128>(Bs, Bb + kt * 64, C);
    __syncthreads();
#pragma unroll
    for (int kk = 0; kk < 2; ++kk) {
      const int koff = (kk * 32 + lhi * 8) ^ swz;
      bf16x8 af[2], bfv[4];
#pragma unroll
      for (int m = 0; m < 2; ++m)
        af[m] = *(const bf16x8*)&As[(wr * 32 + m * 16 + l15) * 64 + koff];
#pragma unroll
      for (int n = 0; n < 4; ++n)
        bfv[n] = *(const bf16x8*)&Bs[(wc * 64 + n * 16 + l15) * 64 + koff];
#pragma unroll
      for (int m = 0; m < 2; ++m)
#pragma unroll
        for (int n = 0; n < 4; ++n)
          acc[m][n] = __builtin_amdgcn_mfma_f32_16x16x32_bf16(af[m], bfv[n], acc[m][n], 0, 0, 0);
    }
    __syncthreads();
  }
#pragma unroll
  for (int n = 0; n < 4; ++n) {
    const int o = nt * 128 + wc * 64 + n * 16 + l15;
    const float bias = qkvb[o];
    const int which = o >> 9, rem = o & 511, hh = rem >> 6, d = rem & 63;
    const size_t bh = (size_t)b * H + hh;
#pragma unroll
    for (int m = 0; m < 2; ++m) {
      const int tbase = mt * 128 + wr * 32 + m * 16 + lhi * 4;
#pragma unroll
      for (int r = 0; r < 4; ++r) {
        float val = acc[m][n][r] + bias;
        if (which == 0) val *= SCLQ;   // fold softmax scale into Q
        const u16 bv = f2bf(val);
        const int t = tbase + r;
        if (which == 0)      qo[(bh * T + t) * CH + d] = bv;
        else if (which == 1) kvo_k[(bh * T + t) * CH + d] = bv;
        else                 kvo_v[(bh * CH + d) * T + t] = bv;
      }
    }
  }
}

// ---------------- flash attention: 8 waves = (kv-group, q-set), 32x32x16 MFMA,
// swapped QK^T, in-register no-max softmax, lsum via ones-column MFMA.
// XCD-swizzled: each XCD owns 4 bh -> K/V L2-resident. ----------------------
__global__ __launch_bounds__(512, 4) void attn_k(const u16* __restrict__ q,
                                                 const u16* __restrict__ k,
                                                 const u16* __restrict__ v,
                                                 u16* __restrict__ at) {
  __shared__ u16 Ks[2][128 * 64];     // pair of K tiles
  __shared__ u16 Vs[2][2][64 * 64];   // pair of V tiles [d][s]
  const int lin = blockIdx.x + (blockIdx.y << 4);
  const int wg = (lin & 7) * 64 + (lin >> 3);   // 512 = 8 x 64, bijective
  const int qt = wg & 15, bh = wg >> 4;
  const int tid = threadIdx.x, lane = tid & 63, w = tid >> 6;
  const int qset = w & 3, grp = w >> 2;
  const int l31 = lane & 31, h = lane >> 5;
  const u16* qb = q + (size_t)bh * T * CH;
  const u16* kb = k + (size_t)bh * T * CH;
  const u16* vb = v + (size_t)bh * CH * T;
  constexpr int NP = T / 128;  // 16 tile-pairs

  // Q B-frags straight from global (q-set owns rows qset*32..qset*32+31)
  bf16x8 qf[4];
  {
    const u16* qp = qb + (size_t)(qt * 128 + qset * 32 + l31) * CH + h * 8;
#pragma unroll
    for (int ks = 0; ks < 4; ++ks) qf[ks] = *(const bf16x8*)(qp + ks * 16);
  }
  // ones B-frag for the lsum MFMA (bf16 1.0 = 0x3F80)
  union { u32 u[4]; bf16x8 v8; } ones;
#pragma unroll
  for (int i = 0; i < 4; ++i) ones.u[i] = 0x3F803F80u;

  // prologue: stage pair 0
  stage_swz_8w<128>(Ks[0], kb, CH);
  stage_swz_8w<64>(Vs[0][0], vb, T);
  stage_swz_8w<64>(Vs[0][1], vb + 64, T);
  asm volatile("s_waitcnt vmcnt(0)" ::: "memory");
  __builtin_amdgcn_s_barrier();
  asm volatile("" ::: "memory");

  f32x16 accO0 = {0.f,0.f,0.f,0.f,0.f,0.f,0.f,0.f,0.f,0.f,0.f,0.f,0.f,0.f,0.f,0.f};
  f32x16 accO1 = accO0;
  f32x16 accL = accO0;   // lsum accumulator: accL[r] = sum_kv P[kv][qrow(r)]
  const int kswz = (l31 & 7) << 3;

  int cur = 0;
  for (int p = 0; p < NP; ++p) {
    // stage next pair first; latency (L2-hit post-swizzle) hides under compute
    if (p + 1 < NP) {
      stage_swz_8w<128>(Ks[cur ^ 1], kb + (size_t)(p + 1) * 128 * CH, CH);
      stage_swz_8w<64>(Vs[cur ^ 1][0], vb + (p + 1) * 128, T);
      stage_swz_8w<64>(Vs[cur ^ 1][1], vb + (p + 1) * 128 + 64, T);
    }
    const u16* Kc = &Ks[cur][grp * 64 * 64];  // this group's K tile
    const u16* Vc = Vs[cur][grp];             // this group's V tile

    // QK^T swapped: accS = S^T[kv][q = l31]
    f32x16 accS0 = {0.f,0.f,0.f,0.f,0.f,0.f,0.f,0.f,0.f,0.f,0.f,0.f,0.f,0.f,0.f,0.f};
    f32x16 accS1 = accS0;
    __builtin_amdgcn_s_setprio(1);
#pragma unroll
    for (int ks = 0; ks < 4; ++ks) {
      const int col = (ks * 16 + h * 8) ^ kswz;
      bf16x8 kf0 = *(const bf16x8*)&Kc[l31 * 64 + col];
      bf16x8 kf1 = *(const bf16x8*)&Kc[(32 + l31) * 64 + col];
      accS0 = __builtin_amdgcn_mfma_f32_32x32x16_bf16(kf0, qf[ks], accS0, 0, 0, 0);
      accS1 = __builtin_amdgcn_mfma_f32_32x32x16_bf16(kf1, qf[ks], accS1, 0, 0, 0);
    }
    __builtin_amdgcn_s_setprio(0);

    // No-max softmax: p = exp2(S) (scale pre-folded into Q); raw v_exp_f32
    // (inputs bounded, no range fixup needed); pack to bf16 pairs
    u32 wd0[8], wd1[8];
#pragma unroll
    for (int i = 0; i < 8; ++i) {
      float pa = __builtin_amdgcn_exp2f(accS0[2 * i]);
      float pb = __builtin_amdgcn_exp2f(accS0[2 * i + 1]);
      asm("v_cvt_pk_bf16_f32 %0, %1, %2" : "=v"(wd0[i]) : "v"(pa), "v"(pb));
    }
#pragma unroll
    for (int i = 0; i < 8; ++i) {
      float pa = __builtin_amdgcn_exp2f(accS1[2 * i]);
      float pb = __builtin_amdgcn_exp2f(accS1[2 * i + 1]);
      asm("v_cvt_pk_bf16_f32 %0, %1, %2" : "=v"(wd1[i]) : "v"(pa), "v"(pb));
    }
    // cross-half exchange in-register (dst.hi<->src.lo)
    pl32swap(wd0[0], wd0[2]); pl32swap(wd0[1], wd0[3]);
    pl32swap(wd0[4], wd0[6]); pl32swap(wd0[5], wd0[7]);
    pl32swap(wd1[0], wd1[2]); pl32swap(wd1[1], wd1[3]);
    pl32swap(wd1[4], wd1[6]); pl32swap(wd1[5], wd1[7]);

    // PV: O[q][d] += P^T[q][s] * V[d][s]; lsum via ones-column MFMA
    __builtin_amdgcn_s_setprio(1);
#pragma unroll
    for (int kt = 0; kt < 2; ++kt) {
      const u32* wd = kt ? wd1 : wd0;
      union { u32 u[4]; bf16x8 v8; } fa, fb;
      fa.u[0] = wd[0]; fa.u[1] = wd[1]; fa.u[2] = wd[2]; fa.u[3] = wd[3];
      fb.u[0] = wd[4]; fb.u[1] = wd[5]; fb.u[2] = wd[6]; fb.u[3] = wd[7];
      const int sA = (kt * 32 + h * 8) ^ kswz;
      const int sB = (kt * 32 + 16 + h * 8) ^ kswz;
      {
        bf16x8 vf0 = *(const bf16x8*)&Vc[l31 * 64 + sA];
        bf16x8 vf1 = *(const bf16x8*)&Vc[l31 * 64 + sB];
        accO0 = __builtin_amdgcn_mfma_f32_32x32x16_bf16(fa.v8, vf0, accO0, 0, 0, 0);
        accO0 = __builtin_amdgcn_mfma_f32_32x32x16_bf16(fb.v8, vf1, accO0, 0, 0, 0);
      }
      {
        bf16x8 vf0 = *(const bf16x8*)&Vc[(32 + l31) * 64 + sA];
        bf16x8 vf1 = *(const bf16x8*)&Vc[(32 + l31) * 64 + sB];
        accO1 = __builtin_amdgcn_mfma_f32_32x32x16_bf16(fa.v8, vf0, accO1, 0, 0, 0);
        accO1 = __builtin_amdgcn_mfma_f32_32x32x16_bf16(fb.v8, vf1, accO1, 0, 0, 0);
      }
      accL = __builtin_amdgcn_mfma_f32_32x32x16_bf16(fa.v8, ones.v8, accL, 0, 0, 0);
      accL = __builtin_amdgcn_mfma_f32_32x32x16_bf16(fb.v8, ones.v8, accL, 0, 0, 0);
    }
    __builtin_amdgcn_s_setprio(0);

    asm volatile("s_waitcnt vmcnt(0)" ::: "memory");
    __builtin_amdgcn_s_barrier();
    asm volatile("" ::: "memory");
    cur ^= 1;
  }

  // combine the two kv-groups via LDS (reuse Ks: 32KB = [128][64] f32)
  float* fO = (float*)&Ks[0][0];
  float* fL = (float*)&Vs[0][0][0];
  if (grp == 1) {
#pragma unroll
    for (int r = 0; r < 16; ++r) {
      const int qrow = (r & 3) + 8 * (r >> 2) + 4 * h;
      float* row = fO + (qset * 32 + qrow) * 64;
      row[l31] = accO0[r];
      row[32 + l31] = accO1[r];
      if (l31 == 0) fL[qset * 32 + qrow] = accL[r];
    }
  }
  __syncthreads();
  if (grp == 0) {
    const int bq = bh >> 3, hh = bh & 7;
#pragma unroll
    for (int r = 0; r < 16; ++r) {
      const int qrow = (r & 3) + 8 * (r >> 2) + 4 * h;
      const float denom = accL[r] + fL[qset * 32 + qrow];
      const float invr = __builtin_amdgcn_rcpf(denom);
      const float* row = fO + (qset * 32 + qrow) * 64;
      const float o0 = accO0[r] + row[l31];
      const float o1 = accO1[r] + row[32 + l31];
      const int t = qt * 128 + qset * 32 + qrow;
      u16* op = at + ((size_t)bq * T + t) * C + hh * 64 + l31;
      op[0]  = f2bf(o0 * invr);
      op[32] = f2bf(o1 * invr);
    }
  }
}

// ---------------- proj bt-GEMM + bias + residual ----------------
// 512 threads / 8 waves (wave tile 16x64), 128M x 64N tiles: 512 blocks
// (2 blocks/CU, 16 waves/CU vs 8 before). XCD-chunked 1D grid.
__global__ __launch_bounds__(512, 2) void proj_gemm_k(const u16* __restrict__ at,
                                                      const u16* __restrict__ wp,
                                                      const float* __restrict__ pb,
                                                      const float* __restrict__ x,
                                                      float* __restrict__ out) {
  __shared__ u16 As[128 * 64];
  __shared__ u16 Bs[64 * 64];
  const int bid = blockIdx.x;
  const int wg = (bid & 7) * 64 + (bid >> 3);   // 512 = 8 x 64, bijective
  const int nt = wg & 7;
  const int mtb = wg >> 3;
  const int mt = mtb & 15, b = mtb >> 4;
  const u16* Ab = at + ((size_t)b * T + mt * 128) * C;
  const u16* Bb = wp + (size_t)nt * 64 * C;
  const int tid = threadIdx.x, lane = tid & 63, w = tid >> 6;
  const int l15 = lane & 15, lhi = lane >> 4;
  const int swz = (l15 & 7) << 3;

  const f32x4 vzero = {0.f, 0.f, 0.f, 0.f};
  f32x4 acc[4];
#pragma unroll
  for (int n = 0; n < 4; ++n) acc[n] = vzero;

  for (int kt = 0; kt < C / 64; ++kt) {
    stage_swz_8w<128>(As, Ab + kt * 64, C);
    stage_swz_8w<64>(Bs, Bb + kt * 64, C);
    __syncthreads();
#pragma unroll
    for (int kk = 0; kk < 2; ++kk) {
      const int koff = (kk * 32 + lhi * 8) ^ swz;
      bf16x8 af = *(const bf16x8*)&As[(w * 16 + l15) * 64 + koff];
      bf16x8 bfv[4];
#pragma unroll
      for (int n = 0; n < 4; ++n)
        bfv[n] = *(const bf16x8*)&Bs[(n * 16 + l15) * 64 + koff];
#pragma unroll
      for (int n = 0; n < 4; ++n)
        acc[n] = __builtin_amdgcn_mfma_f32_16x16x32_bf16(af, bfv[n], acc[n], 0, 0, 0);
    }
    __syncthreads();
  }
#pragma unroll
  for (int n = 0; n < 4; ++n) {
    const int o = nt * 64 + n * 16 + l15;
    const float bias = pb[o];
    const int tbase = mt * 128 + w * 16 + lhi * 4;
#pragma unroll
    for (int r = 0; r < 4; ++r) {
      const int t = tbase + r;
      const size_t idx = ((size_t)b * C + o) * T + t;
      out[idx] = x[idx] + acc[n][r] + bias;
    }
  }
}

extern "C" void kernel_launch(void* const* d_in, const int* in_sizes, int n_in,
                              void* d_out, int out_size, void* d_ws, size_t ws_size,
                              hipStream_t stream) {
  const float* x     = (const float*)d_in[0];
  const float* gsc   = (const float*)d_in[1];
  const float* gbi   = (const float*)d_in[2];
  const float* qkvw  = (const float*)d_in[3];
  const float* qkvb  = (const float*)d_in[4];
  const float* projw = (const float*)d_in[5];
  const float* projb = (const float*)d_in[6];
  float* out = (float*)d_out;

  char* ws = (char*)d_ws;
  float* stats = (float*)ws;
  u16* wq = (u16*)(ws + 1024);
  u16* wp = (u16*)(ws + 1024 + 1572864);
  u16* ht = (u16*)(ws + 2098176);
  u16* qo = (u16*)(ws + 10486784);
  u16* ko = (u16*)(ws + 18875392);
  u16* vo = (u16*)(ws + 27264000);
  u16* at = ht;  // reuse: ht dead after qkv_gemm

  prep_k<<<1152, 256, 0, stream>>>(x, stats, qkvw, wq, 196608, projw, wp, 65536);
  gn_apply_k<<<dim3(T / 32, B), 256, 0, stream>>>(x, stats, gsc, gbi, ht);
  qkv_gemm_k<<<768, 512, 0, stream>>>(ht, wq, qkvb, qo, ko, vo);
  attn_k<<<dim3(T / 128, B * H), 512, 0, stream>>>(qo, ko, vo, at);
  proj_gemm_k<<<512, 512, 0, stream>>>(at, wp, projb, x, out);
}

// Round 10
// 104.402 us; speedup vs baseline: 2.3142x; 1.0925x over previous
//
#include <hip/hip_runtime.h>

typedef short bf16x8 __attribute__((ext_vector_type(8)));
typedef float f32x4 __attribute__((ext_vector_type(4)));
typedef float f32x16 __attribute__((ext_vector_type(16)));
typedef unsigned short u16;
typedef unsigned int u32;

constexpr int B = 4, C = 512, T = 2048, H = 8, G = 32;
constexpr int CH = C / H;   // 64
constexpr int CPG = C / G;  // 16
constexpr float EPS = 1e-5f;
// softmax scale folded into Q: p = exp2(S_raw * 0.125 * log2(e))
constexpr float SCLQ = 0.18033688011112042f;

__device__ __forceinline__ u16 f2bf(float f) {
  union { float f; u32 u; } v; v.f = f;
  return (u16)((v.u + 0x7FFFu + ((v.u >> 16) & 1u)) >> 16);
}

__device__ __forceinline__ u32 cvtpk(float lo, float hi) {
  u32 r;
  asm("v_cvt_pk_bf16_f32 %0, %1, %2" : "=v"(r) : "v"(lo), "v"(hi));
  return r;
}

__device__ __forceinline__ void gload16(const void* g, void* lds) {
  __builtin_amdgcn_global_load_lds(
      (const __attribute__((address_space(1))) void*)g,
      (__attribute__((address_space(3))) void*)lds, 16, 0, 0);
}

// v_permlane32_swap_b32: a.hi <-> b.lo (cross-half exchange for the PV
// A-fragment; VALU pipe, replaces ds_bpermute + cndmask)
__device__ __forceinline__ void pl32swap(u32& a, u32& b) {
  asm("v_permlane32_swap_b32 %0, %1" : "+v"(a), "+v"(b));
}

// XOR-swizzled staging: ROWS x 64 bf16 tile -> linear LDS [ROWS][64].
// Global source column pre-swizzled; reads apply col ^ ((row&7)<<3).
template <int ROWS>  // 512-thread blocks
__device__ __forceinline__ void stage_swz_8w(u16* lds, const u16* gsrc, int ldk) {
  const int tid = threadIdx.x;
  const int w = tid >> 6, lane = tid & 63;
#pragma unroll
  for (int i = 0; i < ROWS / 64; ++i) {
    const int chunk = i * 8 + w;
    const int row = chunk * 8 + (lane >> 3);
    const int col = ((lane & 7) * 8) ^ ((row & 7) << 3);
    gload16(gsrc + (size_t)row * ldk + col, (char*)lds + chunk * 1024);
  }
}

// ---------------- prep: GroupNorm stats (first! long pole) + weight casts ----
__global__ __launch_bounds__(256) void prep_k(const float* __restrict__ x,
                                              float* __restrict__ stats,
                                              const float* __restrict__ s1,
                                              u16* __restrict__ d1, int n1,
                                              const float* __restrict__ s2,
                                              u16* __restrict__ d2, int n2) {
  __shared__ float red[8];
  const int bid = blockIdx.x;
  if (bid >= 128) {  // ---- weight cast path ----
    int i = (bid - 128) * 256 + threadIdx.x;
    const float4* src = (const float4*)s1;
    uint2* dst = (uint2*)d1;
    if (i >= n1) { i -= n1; if (i >= n2) return; src = (const float4*)s2; dst = (uint2*)d2; }
    float4 v = src[i];
    uint2 pk;
    pk.x = cvtpk(v.x, v.y);
    pk.y = cvtpk(v.z, v.w);
    dst[i] = pk;
    return;
  }
  // ---- gn_stats path (blocks 0..127 start immediately) ----
  const int bg = bid;
  const float4* xp = (const float4*)(x + (size_t)bg * CPG * T);
  float s = 0.f, ss = 0.f;
  for (int i = threadIdx.x; i < CPG * T / 4; i += 256) {
    float4 v = xp[i];
    s += v.x + v.y + v.z + v.w;
    ss += v.x * v.x + v.y * v.y + v.z * v.z + v.w * v.w;
  }
  for (int off = 32; off; off >>= 1) {
    s += __shfl_down(s, off);
    ss += __shfl_down(ss, off);
  }
  const int w = threadIdx.x >> 6;
  if ((threadIdx.x & 63) == 0) { red[w] = s; red[4 + w] = ss; }
  __syncthreads();
  if (threadIdx.x == 0) {
    float S = red[0] + red[1] + red[2] + red[3];
    float SS = red[4] + red[5] + red[6] + red[7];
    const float inv = 1.f / (float)(CPG * T);
    float mean = S * inv;
    float var = SS * inv - mean * mean;
    stats[bg * 2] = mean;
    stats[bg * 2 + 1] = rsqrtf(var + EPS);
  }
}

__global__ __launch_bounds__(256) void gn_apply_k(const float* __restrict__ x,
                                                  const float* __restrict__ stats,
                                                  const float* __restrict__ gsc,
                                                  const float* __restrict__ gbi,
                                                  u16* __restrict__ ht) {
  const int b = blockIdx.y;
  const int t0 = blockIdx.x * 16;
#pragma unroll
  for (int p = 0; p < 2; ++p) {
    const int c = p * 256 + threadIdx.x;
    const int bg = b * G + (c >> 4);
    const float mean = stats[bg * 2], rstd = stats[bg * 2 + 1];
    const float sc = gsc[c] * rstd;
    const float bi = gbi[c] - mean * sc;
    const float4* xp = (const float4*)(x + ((size_t)b * C + c) * T + t0);
#pragma unroll
    for (int j = 0; j < 4; ++j) {
      float4 v = xp[j];
      const int t = t0 + j * 4;
      u16* hp = ht + ((size_t)b * T + t) * C + c;
      hp[0]     = f2bf(v.x * sc + bi);
      hp[C]     = f2bf(v.y * sc + bi);
      hp[2 * C] = f2bf(v.z * sc + bi);
      hp[3 * C] = f2bf(v.w * sc + bi);
    }
  }
}

// ---------------- QKV bt-GEMM: C'[t][o] = sum_c h_t[t][c] * W[o][c] ----------------
// 512 threads / 8 waves (wave tile 32x64), double-buffered LDS, attn-style
// pipelined loop: stage(next) issued before compute(cur), ONE barrier/K-step.
// XCD-chunked 1D grid (L2-resident A-panel + B tiles).
__global__ __launch_bounds__(512, 2) void qkv_gemm_k(const u16* __restrict__ ht,
                                                     const u16* __restrict__ wq,
                                                     const float* __restrict__ qkvb,
                                                     u16* __restrict__ qo,
                                                     u16* __restrict__ kvo_k,
                                                     u16* __restrict__ kvo_v) {
  __shared__ u16 As[2][128 * 64];
  __shared__ u16 Bs[2][128 * 64];
  const int bid = blockIdx.x;
  const int wg = (bid & 7) * 96 + (bid >> 3);   // 768 = 8 x 96, bijective
  const int nt = wg % 12;
  const int mtb = wg / 12;
  const int mt = mtb & 15, b = mtb >> 4;
  const u16* Ab = ht + ((size_t)b * T + mt * 128) * C;
  const u16* Bb = wq + (size_t)nt * 128 * C;
  const int tid = threadIdx.x, lane = tid & 63, w = tid >> 6;
  const int wr = w >> 1, wc = w & 1, l15 = lane & 15, lhi = lane >> 4;
  const int swz = (l15 & 7) << 3;
  constexpr int NK = C / 64;  // 8

  const f32x4 vzero = {0.f, 0.f, 0.f, 0.f};
  f32x4 acc[2][4];
#pragma unroll
  for (int m = 0; m < 2; ++m)
#pragma unroll
    for (int n = 0; n < 4; ++n) acc[m][n] = vzero;

  stage_swz_8w<128>(As[0], Ab, C);
  stage_swz_8w<128>(Bs[0], Bb, C);
  asm volatile("s_waitcnt vmcnt(0)" ::: "memory");
  __builtin_amdgcn_s_barrier();
  asm volatile("" ::: "memory");

  int cur = 0;
  for (int kt = 0; kt < NK; ++kt) {
    if (kt + 1 < NK) {  // issue next tile's stage; hides under MFMA below
      stage_swz_8w<128>(As[cur ^ 1], Ab + (kt + 1) * 64, C);
      stage_swz_8w<128>(Bs[cur ^ 1], Bb + (kt + 1) * 64, C);
    }
#pragma unroll
    for (int kk = 0; kk < 2; ++kk) {
      const int koff = (kk * 32 + lhi * 8) ^ swz;
      bf16x8 af[2], bfv[4];
#pragma unroll
      for (int m = 0; m < 2; ++m)
        af[m] = *(const bf16x8*)&As[cur][(wr * 32 + m * 16 + l15) * 64 + koff];
#pragma unroll
      for (int n = 0; n < 4; ++n)
        bfv[n] = *(const bf16x8*)&Bs[cur][(wc * 64 + n * 16 + l15) * 64 + koff];
#pragma unroll
      for (int m = 0; m < 2; ++m)
#pragma unroll
        for (int n = 0; n < 4; ++n)
          acc[m][n] = __builtin_amdgcn_mfma_f32_16x16x32_bf16(af[m], bfv[n], acc[m][n], 0, 0, 0);
    }
    if (kt + 1 < NK) {
      asm volatile("s_waitcnt vmcnt(0)" ::: "memory");
      __builtin_amdgcn_s_barrier();
      asm volatile("" ::: "memory");
    }
    cur ^= 1;
  }
#pragma unroll
  for (int n = 0; n < 4; ++n) {
    const int o = nt * 128 + wc * 64 + n * 16 + l15;
    const float bias = qkvb[o];
    const int which = o >> 9, rem = o & 511, hh = rem >> 6, d = rem & 63;
    const size_t bh = (size_t)b * H + hh;
#pragma unroll
    for (int m = 0; m < 2; ++m) {
      const int tbase = mt * 128 + wr * 32 + m * 16 + lhi * 4;
      float v0 = acc[m][n][0] + bias, v1 = acc[m][n][1] + bias;
      float v2 = acc[m][n][2] + bias, v3 = acc[m][n][3] + bias;
      if (which == 0) { v0 *= SCLQ; v1 *= SCLQ; v2 *= SCLQ; v3 *= SCLQ; }
      const u32 w01 = cvtpk(v0, v1), w23 = cvtpk(v2, v3);
      if (which == 2) {
        // V: [bh][d][t], 4 consecutive t -> one 8B store
        uint2 pk; pk.x = w01; pk.y = w23;
        *(uint2*)&kvo_v[(bh * CH + d) * T + tbase] = pk;
      } else {
        u16* dst = (which == 0) ? qo : kvo_k;
        dst[(bh * T + tbase) * CH + d]     = (u16)(w01 & 0xffff);
        dst[(bh * T + tbase + 1) * CH + d] = (u16)(w01 >> 16);
        dst[(bh * T + tbase + 2) * CH + d] = (u16)(w23 & 0xffff);
        dst[(bh * T + tbase + 3) * CH + d] = (u16)(w23 >> 16);
      }
    }
  }
}

// ---------------- flash attention: 8 waves = (kv-group, q-set), 32x32x16 MFMA,
// swapped QK^T, in-register no-max softmax, lsum via ones-column MFMA.
// XCD-swizzled: each XCD owns 4 bh -> K/V L2-resident. ----------------------
__global__ __launch_bounds__(512, 4) void attn_k(const u16* __restrict__ q,
                                                 const u16* __restrict__ k,
                                                 const u16* __restrict__ v,
                                                 u16* __restrict__ at) {
  __shared__ u16 Ks[2][128 * 64];     // pair of K tiles
  __shared__ u16 Vs[2][2][64 * 64];   // pair of V tiles [d][s]
  const int lin = blockIdx.x + (blockIdx.y << 4);
  const int wg = (lin & 7) * 64 + (lin >> 3);   // 512 = 8 x 64, bijective
  const int qt = wg & 15, bh = wg >> 4;
  const int tid = threadIdx.x, lane = tid & 63, w = tid >> 6;
  const int qset = w & 3, grp = w >> 2;
  const int l31 = lane & 31, h = lane >> 5;
  const u16* qb = q + (size_t)bh * T * CH;
  const u16* kb = k + (size_t)bh * T * CH;
  const u16* vb = v + (size_t)bh * CH * T;
  constexpr int NP = T / 128;  // 16 tile-pairs

  // Q B-frags straight from global (q-set owns rows qset*32..qset*32+31)
  bf16x8 qf[4];
  {
    const u16* qp = qb + (size_t)(qt * 128 + qset * 32 + l31) * CH + h * 8;
#pragma unroll
    for (int ks = 0; ks < 4; ++ks) qf[ks] = *(const bf16x8*)(qp + ks * 16);
  }
  // ones B-frag for the lsum MFMA (bf16 1.0 = 0x3F80)
  union { u32 u[4]; bf16x8 v8; } ones;
#pragma unroll
  for (int i = 0; i < 4; ++i) ones.u[i] = 0x3F803F80u;

  // prologue: stage pair 0
  stage_swz_8w<128>(Ks[0], kb, CH);
  stage_swz_8w<64>(Vs[0][0], vb, T);
  stage_swz_8w<64>(Vs[0][1], vb + 64, T);
  asm volatile("s_waitcnt vmcnt(0)" ::: "memory");
  __builtin_amdgcn_s_barrier();
  asm volatile("" ::: "memory");

  f32x16 accO0 = {0.f,0.f,0.f,0.f,0.f,0.f,0.f,0.f,0.f,0.f,0.f,0.f,0.f,0.f,0.f,0.f};
  f32x16 accO1 = accO0;
  f32x16 accL = accO0;   // lsum accumulator: accL[r] = sum_kv P[kv][qrow(r)]
  const int kswz = (l31 & 7) << 3;

  int cur = 0;
  for (int p = 0; p < NP; ++p) {
    // stage next pair first; latency (L2-hit post-swizzle) hides under compute
    if (p + 1 < NP) {
      stage_swz_8w<128>(Ks[cur ^ 1], kb + (size_t)(p + 1) * 128 * CH, CH);
      stage_swz_8w<64>(Vs[cur ^ 1][0], vb + (p + 1) * 128, T);
      stage_swz_8w<64>(Vs[cur ^ 1][1], vb + (p + 1) * 128 + 64, T);
    }
    const u16* Kc = &Ks[cur][grp * 64 * 64];  // this group's K tile
    const u16* Vc = Vs[cur][grp];             // this group's V tile

    // QK^T swapped: accS = S^T[kv][q = l31]
    f32x16 accS0 = {0.f,0.f,0.f,0.f,0.f,0.f,0.f,0.f,0.f,0.f,0.f,0.f,0.f,0.f,0.f,0.f};
    f32x16 accS1 = accS0;
    __builtin_amdgcn_s_setprio(1);
#pragma unroll
    for (int ks = 0; ks < 4; ++ks) {
      const int col = (ks * 16 + h * 8) ^ kswz;
      bf16x8 kf0 = *(const bf16x8*)&Kc[l31 * 64 + col];
      bf16x8 kf1 = *(const bf16x8*)&Kc[(32 + l31) * 64 + col];
      accS0 = __builtin_amdgcn_mfma_f32_32x32x16_bf16(kf0, qf[ks], accS0, 0, 0, 0);
      accS1 = __builtin_amdgcn_mfma_f32_32x32x16_bf16(kf1, qf[ks], accS1, 0, 0, 0);
    }
    __builtin_amdgcn_s_setprio(0);

    // No-max softmax: p = exp2(S) (scale pre-folded into Q); raw v_exp_f32
    // (inputs bounded, no range fixup needed); pack to bf16 pairs
    u32 wd0[8], wd1[8];
#pragma unroll
    for (int i = 0; i < 8; ++i) {
      float pa = __builtin_amdgcn_exp2f(accS0[2 * i]);
      float pb = __builtin_amdgcn_exp2f(accS0[2 * i + 1]);
      asm("v_cvt_pk_bf16_f32 %0, %1, %2" : "=v"(wd0[i]) : "v"(pa), "v"(pb));
    }
#pragma unroll
    for (int i = 0; i < 8; ++i) {
      float pa = __builtin_amdgcn_exp2f(accS1[2 * i]);
      float pb = __builtin_amdgcn_exp2f(accS1[2 * i + 1]);
      asm("v_cvt_pk_bf16_f32 %0, %1, %2" : "=v"(wd1[i]) : "v"(pa), "v"(pb));
    }
    // cross-half exchange in-register (dst.hi<->src.lo)
    pl32swap(wd0[0], wd0[2]); pl32swap(wd0[1], wd0[3]);
    pl32swap(wd0[4], wd0[6]); pl32swap(wd0[5], wd0[7]);
    pl32swap(wd1[0], wd1[2]); pl32swap(wd1[1], wd1[3]);
    pl32swap(wd1[4], wd1[6]); pl32swap(wd1[5], wd1[7]);

    // PV: O[q][d] += P^T[q][s] * V[d][s]; lsum via ones-column MFMA
    __builtin_amdgcn_s_setprio(1);
#pragma unroll
    for (int kt = 0; kt < 2; ++kt) {
      const u32* wd = kt ? wd1 : wd0;
      union { u32 u[4]; bf16x8 v8; } fa, fb;
      fa.u[0] = wd[0]; fa.u[1] = wd[1]; fa.u[2] = wd[2]; fa.u[3] = wd[3];
      fb.u[0] = wd[4]; fb.u[1] = wd[5]; fb.u[2] = wd[6]; fb.u[3] = wd[7];
      const int sA = (kt * 32 + h * 8) ^ kswz;
      const int sB = (kt * 32 + 16 + h * 8) ^ kswz;
      {
        bf16x8 vf0 = *(const bf16x8*)&Vc[l31 * 64 + sA];
        bf16x8 vf1 = *(const bf16x8*)&Vc[l31 * 64 + sB];
        accO0 = __builtin_amdgcn_mfma_f32_32x32x16_bf16(fa.v8, vf0, accO0, 0, 0, 0);
        accO0 = __builtin_amdgcn_mfma_f32_32x32x16_bf16(fb.v8, vf1, accO0, 0, 0, 0);
      }
      {
        bf16x8 vf0 = *(const bf16x8*)&Vc[(32 + l31) * 64 + sA];
        bf16x8 vf1 = *(const bf16x8*)&Vc[(32 + l31) * 64 + sB];
        accO1 = __builtin_amdgcn_mfma_f32_32x32x16_bf16(fa.v8, vf0, accO1, 0, 0, 0);
        accO1 = __builtin_amdgcn_mfma_f32_32x32x16_bf16(fb.v8, vf1, accO1, 0, 0, 0);
      }
      accL = __builtin_amdgcn_mfma_f32_32x32x16_bf16(fa.v8, ones.v8, accL, 0, 0, 0);
      accL = __builtin_amdgcn_mfma_f32_32x32x16_bf16(fb.v8, ones.v8, accL, 0, 0, 0);
    }
    __builtin_amdgcn_s_setprio(0);

    asm volatile("s_waitcnt vmcnt(0)" ::: "memory");
    __builtin_amdgcn_s_barrier();
    asm volatile("" ::: "memory");
    cur ^= 1;
  }

  // combine the two kv-groups via LDS (reuse Ks: 32KB = [128][64] f32)
  float* fO = (float*)&Ks[0][0];
  float* fL = (float*)&Vs[0][0][0];
  if (grp == 1) {
#pragma unroll
    for (int r = 0; r < 16; ++r) {
      const int qrow = (r & 3) + 8 * (r >> 2) + 4 * h;
      float* row = fO + (qset * 32 + qrow) * 64;
      row[l31] = accO0[r];
      row[32 + l31] = accO1[r];
      if (l31 == 0) fL[qset * 32 + qrow] = accL[r];
    }
  }
  __syncthreads();
  if (grp == 0) {
    const int bq = bh >> 3, hh = bh & 7;
#pragma unroll
    for (int r = 0; r < 16; ++r) {
      const int qrow = (r & 3) + 8 * (r >> 2) + 4 * h;
      const float denom = accL[r] + fL[qset * 32 + qrow];
      const float invr = __builtin_amdgcn_rcpf(denom);
      const float* row = fO + (qset * 32 + qrow) * 64;
      const float o0 = accO0[r] + row[l31];
      const float o1 = accO1[r] + row[32 + l31];
      const int t = qt * 128 + qset * 32 + qrow;
      u16* op = at + ((size_t)bq * T + t) * C + hh * 64 + l31;
      op[0]  = f2bf(o0 * invr);
      op[32] = f2bf(o1 * invr);
    }
  }
}

// ---------------- proj bt-GEMM + bias + residual ----------------
// 512 threads / 8 waves (wave tile 16x64), dbuf pipelined loop, one
// barrier/K-step. float4 residual+store. XCD-chunked 1D grid.
__global__ __launch_bounds__(512, 2) void proj_gemm_k(const u16* __restrict__ at,
                                                      const u16* __restrict__ wp,
                                                      const float* __restrict__ pb,
                                                      const float* __restrict__ x,
                                                      float* __restrict__ out) {
  __shared__ u16 As[2][128 * 64];
  __shared__ u16 Bs[2][64 * 64];
  const int bid = blockIdx.x;
  const int wg = (bid & 7) * 64 + (bid >> 3);   // 512 = 8 x 64, bijective
  const int nt = wg & 7;
  const int mtb = wg >> 3;
  const int mt = mtb & 15, b = mtb >> 4;
  const u16* Ab = at + ((size_t)b * T + mt * 128) * C;
  const u16* Bb = wp + (size_t)nt * 64 * C;
  const int tid = threadIdx.x, lane = tid & 63, w = tid >> 6;
  const int l15 = lane & 15, lhi = lane >> 4;
  const int swz = (l15 & 7) << 3;
  constexpr int NK = C / 64;  // 8

  const f32x4 vzero = {0.f, 0.f, 0.f, 0.f};
  f32x4 acc[4];
#pragma unroll
  for (int n = 0; n < 4; ++n) acc[n] = vzero;

  stage_swz_8w<128>(As[0], Ab, C);
  stage_swz_8w<64>(Bs[0], Bb, C);
  asm volatile("s_waitcnt vmcnt(0)" ::: "memory");
  __builtin_amdgcn_s_barrier();
  asm volatile("" ::: "memory");

  int cur = 0;
  for (int kt = 0; kt < NK; ++kt) {
    if (kt + 1 < NK) {
      stage_swz_8w<128>(As[cur ^ 1], Ab + (kt + 1) * 64, C);
      stage_swz_8w<64>(Bs[cur ^ 1], Bb + (kt + 1) * 64, C);
    }
#pragma unroll
    for (int kk = 0; kk < 2; ++kk) {
      const int koff = (kk * 32 + lhi * 8) ^ swz;
      bf16x8 af = *(const bf16x8*)&As[cur][(w * 16 + l15) * 64 + koff];
      bf16x8 bfv[4];
#pragma unroll
      for (int n = 0; n < 4; ++n)
        bfv[n] = *(const bf16x8*)&Bs[cur][(n * 16 + l15) * 64 + koff];
#pragma unroll
      for (int n = 0; n < 4; ++n)
        acc[n] = __builtin_amdgcn_mfma_f32_16x16x32_bf16(af, bfv[n], acc[n], 0, 0, 0);
    }
    if (kt + 1 < NK) {
      asm volatile("s_waitcnt vmcnt(0)" ::: "memory");
      __builtin_amdgcn_s_barrier();
      asm volatile("" ::: "memory");
    }
    cur ^= 1;
  }
#pragma unroll
  for (int n = 0; n < 4; ++n) {
    const int o = nt * 64 + n * 16 + l15;
    const float bias = pb[o];
    const int tbase = mt * 128 + w * 16 + lhi * 4;
    const size_t idx = ((size_t)b * C + o) * T + tbase;
    const float4 xv = *(const float4*)&x[idx];
    float4 ov;
    ov.x = xv.x + acc[n][0] + bias;
    ov.y = xv.y + acc[n][1] + bias;
    ov.z = xv.z + acc[n][2] + bias;
    ov.w = xv.w + acc[n][3] + bias;
    *(float4*)&out[idx] = ov;
  }
}

extern "C" void kernel_launch(void* const* d_in, const int* in_sizes, int n_in,
                              void* d_out, int out_size, void* d_ws, size_t ws_size,
                              hipStream_t stream) {
  const float* x     = (const float*)d_in[0];
  const float* gsc   = (const float*)d_in[1];
  const float* gbi   = (const float*)d_in[2];
  const float* qkvw  = (const float*)d_in[3];
  const float* qkvb  = (const float*)d_in[4];
  const float* projw = (const float*)d_in[5];
  const float* projb = (const float*)d_in[6];
  float* out = (float*)d_out;

  char* ws = (char*)d_ws;
  float* stats = (float*)ws;
  u16* wq = (u16*)(ws + 1024);
  u16* wp = (u16*)(ws + 1024 + 1572864);
  u16* ht = (u16*)(ws + 2098176);
  u16* qo = (u16*)(ws + 10486784);
  u16* ko = (u16*)(ws + 18875392);
  u16* vo = (u16*)(ws + 27264000);
  u16* at = ht;  // reuse: ht dead after qkv_gemm

  prep_k<<<1152, 256, 0, stream>>>(x, stats, qkvw, wq, 196608, projw, wp, 65536);
  gn_apply_k<<<dim3(T / 16, B), 256, 0, stream>>>(x, stats, gsc, gbi, ht);
  qkv_gemm_k<<<768, 512, 0, stream>>>(ht, wq, qkvb, qo, ko, vo);
  attn_k<<<dim3(T / 128, B * H), 512, 0, stream>>>(qo, ko, vo, at);
  proj_gemm_k<<<512, 512, 0, stream>>>(at, wp, projb, x, out);
}